// Round 2
// baseline (432.498 us; speedup 1.0000x reference)
//
#include <hip/hip_runtime.h>
#include <stdint.h>

typedef unsigned short u16;
typedef __bf16 bf16x8 __attribute__((ext_vector_type(8)));
typedef float f32x4 __attribute__((ext_vector_type(4)));
typedef u16 ushort8 __attribute__((ext_vector_type(8)));

#define SB 8
#define SS 2048
#define SH 1024
#define MTOT (SB*SS)
#define LOG2E 1.44269504088896f
#define NEG_INF (-__builtin_inff())

typedef __attribute__((address_space(3))) void lds_void;
typedef __attribute__((address_space(1))) const void gbl_void;

__device__ __forceinline__ float bf2f(u16 v) {
    union { unsigned int u; float f; } x; x.u = ((unsigned int)v) << 16; return x.f;
}
__device__ __forceinline__ u16 f2bf(float f) {
    unsigned int u = __builtin_bit_cast(unsigned int, f);
    u += 0x7fffu + ((u >> 16) & 1u);
    return (u16)(u >> 16);
}

// ---------------- fp32 -> bf16 conversion (vectorized, 8 elems/thread) ----
__global__ void cvt_f32_bf16(const float* __restrict__ in, u16* __restrict__ out, int n8) {
    int i = blockIdx.x * 256 + threadIdx.x;
    if (i >= n8) return;
    const float4* p = (const float4*)(in + (size_t)i * 8);
    float4 a = p[0], b = p[1];
    ushort8 r;
    r[0] = f2bf(a.x); r[1] = f2bf(a.y); r[2] = f2bf(a.z); r[3] = f2bf(a.w);
    r[4] = f2bf(b.x); r[5] = f2bf(b.y); r[6] = f2bf(b.z); r[7] = f2bf(b.w);
    *(ushort8*)(out + (size_t)i * 8) = r;
}

// ---------------- shared GEMM building blocks (m97 structure) -------------
// LDS tile layout: linear [128][64] bf16 (u16), 16 KiB per operand.
__device__ __forceinline__ void stage_tile(const u16* __restrict__ g, int ld,
                                           u16* lds, int w, int l) {
#pragma unroll
    for (int i = 0; i < 4; i++) {
        int chunk = i * 4 + w;            // 0..15, wave-uniform
        int r = chunk * 8 + (l >> 3);     // row 0..127
        int c = (l & 7) * 8;              // col elem
        __builtin_amdgcn_global_load_lds(
            (gbl_void*)(g + (size_t)r * ld + c),
            (lds_void*)(lds + chunk * 512), 16, 0, 0);
    }
}

__device__ __forceinline__ void mfma_tile(const u16* As, const u16* Bs,
                                          f32x4 acc[4][4], int w, int l) {
    int wr = (w >> 1) * 64, wc = (w & 1) * 64;
    int lr = l & 15, lk = (l >> 4) * 8;
#pragma unroll
    for (int kk = 0; kk < 2; kk++) {
        bf16x8 af[4], bb[4];
#pragma unroll
        for (int m = 0; m < 4; m++)
            af[m] = *(const bf16x8*)(const void*)(As + (wr + m * 16 + lr) * 64 + kk * 32 + lk);
#pragma unroll
        for (int n = 0; n < 4; n++)
            bb[n] = *(const bf16x8*)(const void*)(Bs + (wc + n * 16 + lr) * 64 + kk * 32 + lk);
#pragma unroll
        for (int m = 0; m < 4; m++)
#pragma unroll
            for (int n = 0; n < 4; n++)
                acc[m][n] = __builtin_amdgcn_mfma_f32_16x16x32_bf16(af[m], bb[n], acc[m][n], 0, 0, 0);
    }
}

// ---------------- QKV projection: C = X @ W^T, store bf16 ----------------
__global__ __launch_bounds__(256, 2) void gemm_qkv(
    const u16* __restrict__ X, const u16* __restrict__ W,
    u16* __restrict__ Q, u16* __restrict__ Kd, u16* __restrict__ Vd) {
    __shared__ u16 As[128 * 64];
    __shared__ u16 Bs[128 * 64];
    int tid = threadIdx.x, w = tid >> 6, l = tid & 63;
    int mt = blockIdx.x, by = blockIdx.y;
    int wsel = by >> 3, nt = by & 7;
    const u16* A = X + (size_t)mt * 128 * SH;
    const u16* Bt = W + (size_t)wsel * SH * SH + (size_t)nt * 128 * SH;
    f32x4 acc[4][4];
#pragma unroll
    for (int m = 0; m < 4; m++)
#pragma unroll
        for (int n = 0; n < 4; n++) acc[m][n] = (f32x4){0.f, 0.f, 0.f, 0.f};
    for (int k0 = 0; k0 < SH; k0 += 64) {
        stage_tile(A + k0, SH, As, w, l);
        stage_tile(Bt + k0, SH, Bs, w, l);
        __syncthreads();
        mfma_tile(As, Bs, acc, w, l);
        __syncthreads();
    }
    u16* out = (wsel == 0 ? Q : (wsel == 1 ? Kd : Vd)) + (size_t)mt * 128 * SH + nt * 128;
    int wr = (w >> 1) * 64, wc = (w & 1) * 64, g = l >> 4, c = l & 15;
#pragma unroll
    for (int m = 0; m < 4; m++)
#pragma unroll
        for (int j = 0; j < 4; j++) {
            size_t ro = (size_t)(wr + m * 16 + g * 4 + j) * SH;
#pragma unroll
            for (int n = 0; n < 4; n++)
                out[ro + wc + n * 16 + c] = f2bf(acc[m][n][j]);
        }
}

// ---------------- V transpose: Vt[b][o][s] = V[b*S+s][o] ------------------
__global__ void transpose_v(const u16* __restrict__ V, u16* __restrict__ Vt) {
    __shared__ u16 t[64][80];
    int s0 = blockIdx.x * 64, o0 = blockIdx.y * 64, b = blockIdx.z;
    const u16* src = V + (size_t)b * SS * SH;
    u16* dst = Vt + (size_t)b * SH * SS;
    int tid = threadIdx.x;
#pragma unroll
    for (int it = 0; it < 2; it++) {
        int idx = it * 256 + tid;
        int r = idx >> 3, gq = idx & 7;
        *(ushort8*)&t[r][gq * 8] = *(const ushort8*)&src[(size_t)(s0 + r) * SH + o0 + gq * 8];
    }
    __syncthreads();
#pragma unroll
    for (int it = 0; it < 2; it++) {
        int idx = it * 256 + tid;
        int rr = idx >> 3, cc = idx & 7;
        ushort8 v;
#pragma unroll
        for (int e = 0; e < 8; e++) v[e] = t[cc * 8 + e][rr];
        *(ushort8*)&dst[(size_t)(o0 + rr) * SS + s0 + cc * 8] = v;
    }
}

// ---------------- Scores: S = QK^T/32, lower-tri tiles; write Ptilde + stats
__global__ __launch_bounds__(256, 2) void gemm_scores(
    const u16* __restrict__ Q, const u16* __restrict__ K,
    u16* __restrict__ P, float* __restrict__ mb, float* __restrict__ lb,
    const int* __restrict__ amask) {
    __shared__ u16 As[128 * 64];
    __shared__ u16 Bs[128 * 64];
    int tid = threadIdx.x, w = tid >> 6, l = tid & 63;
    int b = blockIdx.y, t = blockIdx.x;
    int qt = (int)((sqrtf(8.f * (float)t + 1.f) - 1.f) * 0.5f);
    while ((qt + 1) * (qt + 2) / 2 <= t) qt++;
    while (qt * (qt + 1) / 2 > t) qt--;
    int kt = t - qt * (qt + 1) / 2;
    const u16* A = Q + ((size_t)b * SS + (size_t)qt * 128) * SH;
    const u16* Bt = K + ((size_t)b * SS + (size_t)kt * 128) * SH;
    f32x4 acc[4][4];
#pragma unroll
    for (int m = 0; m < 4; m++)
#pragma unroll
        for (int n = 0; n < 4; n++) acc[m][n] = (f32x4){0.f, 0.f, 0.f, 0.f};
    for (int k0 = 0; k0 < SH; k0 += 64) {
        stage_tile(A + k0, SH, As, w, l);
        stage_tile(Bt + k0, SH, Bs, w, l);
        __syncthreads();
        mfma_tile(As, Bs, acc, w, l);
        __syncthreads();
    }
    int wr = (w >> 1) * 64, wc = (w & 1) * 64, g = l >> 4, c = l & 15;
    int q0 = qt * 128 + wr;
    int k0w = kt * 128 + wc;
    int cglob = kt * 2 + (w & 1);
    u16* Pb = P + (size_t)b * SS * SS;
    float* mbb = mb + (size_t)b * SS * 32;
    float* lbb = lb + (size_t)b * SS * 32;
    int kg[4], kv[4];
#pragma unroll
    for (int n = 0; n < 4; n++) { kg[n] = k0w + n * 16 + c; kv[n] = amask[b * SS + kg[n]]; }
#pragma unroll
    for (int m = 0; m < 4; m++) {
#pragma unroll
        for (int j = 0; j < 4; j++) {
            int qg = q0 + m * 16 + g * 4 + j;
            float sv[4]; float mx = NEG_INF;
#pragma unroll
            for (int n = 0; n < 4; n++) {
                float s = acc[m][n][j] * 0.03125f;   // 1/sqrt(1024)
                bool ok = (kg[n] <= qg) && (kv[n] != 0);
                s = ok ? s : NEG_INF;
                sv[n] = s; mx = fmaxf(mx, s);
            }
#pragma unroll
            for (int d = 1; d < 16; d <<= 1) mx = fmaxf(mx, __shfl_xor(mx, d, 64));
            float ls = 0.f;
#pragma unroll
            for (int n = 0; n < 4; n++) {
                float p = (sv[n] == NEG_INF) ? 0.f : exp2f((sv[n] - mx) * LOG2E);
                sv[n] = p; ls += p;
            }
#pragma unroll
            for (int d = 1; d < 16; d <<= 1) ls += __shfl_xor(ls, d, 64);
            size_t prow = (size_t)qg * SS;
#pragma unroll
            for (int n = 0; n < 4; n++) Pb[prow + kg[n]] = f2bf(sv[n]);
            if (c == 0) { mbb[(size_t)qg * 32 + cglob] = mx; lbb[(size_t)qg * 32 + cglob] = ls; }
        }
    }
}

// ---------------- Combine stats -> per-chunk scale ------------------------
__global__ void combine_stats(const float* __restrict__ mb, const float* __restrict__ lb,
                              float* __restrict__ sb, const int* __restrict__ amask) {
    int row = blockIdx.x * 4 + (threadIdx.x >> 6);
    int l = threadIdx.x & 63;
    int b = row >> 11, q = row & 2047;
    int cmax = q >> 6;
    float mc = NEG_INF, lc = 0.f;
    if (l < 32 && l <= cmax) { mc = mb[(size_t)row * 32 + l]; lc = lb[(size_t)row * 32 + l]; }
    float mstar = mc;
#pragma unroll
    for (int d = 1; d < 64; d <<= 1) mstar = fmaxf(mstar, __shfl_xor(mstar, d, 64));
    float term = (mc > NEG_INF) ? lc * exp2f((mc - mstar) * LOG2E) : 0.f;
    float L = term;
#pragma unroll
    for (int d = 1; d < 64; d <<= 1) L += __shfl_xor(L, d, 64);
    int qv = amask[b * SS + q];
    float inv = (qv != 0 && L > 0.f) ? 1.0f / L : 0.f;
    float sc = (mc > NEG_INF) ? exp2f((mc - mstar) * LOG2E) * inv : 0.f;
    if (l < 32) sb[(size_t)row * 32 + l] = sc;
}

// ---------------- PV: O = (scale*Ptilde) @ Vt^T, fp32 out, causal K-bound -
__global__ __launch_bounds__(256, 2) void gemm_pv(
    const u16* __restrict__ P, const u16* __restrict__ Vt,
    const float* __restrict__ sb, float* __restrict__ Out) {
    __shared__ u16 As[128 * 64];
    __shared__ u16 Bs[128 * 64];
    int tid = threadIdx.x, w = tid >> 6, l = tid & 63;
    int b = blockIdx.y;
    int qt = blockIdx.x >> 3, nt = blockIdx.x & 7;
    const u16* Ab = P + (size_t)b * SS * SS + (size_t)qt * 128 * SS;
    const u16* Bt = Vt + (size_t)b * SH * SS + (size_t)nt * 128 * SS;
    const float* scl = sb + ((size_t)b * SS + (size_t)qt * 128) * 32;
    int ksize = (qt + 1) * 128;
    f32x4 acc[4][4];
#pragma unroll
    for (int m = 0; m < 4; m++)
#pragma unroll
        for (int n = 0; n < 4; n++) acc[m][n] = (f32x4){0.f, 0.f, 0.f, 0.f};
    for (int k0 = 0; k0 < ksize; k0 += 64) {
        // A path: reg-stage Ptilde with fused normalization scale
#pragma unroll
        for (int i = 0; i < 4; i++) {
            int chunk = i * 4 + w;
            int r = chunk * 8 + (l >> 3);
            int cc = (l & 7) * 8;
            ushort8 pv = *(const ushort8*)(Ab + (size_t)r * SS + k0 + cc);
            float sc = scl[r * 32 + (k0 >> 6)];
            ushort8 ov;
#pragma unroll
            for (int e = 0; e < 8; e++) ov[e] = f2bf(bf2f(pv[e]) * sc);
            *(ushort8*)(As + chunk * 512 + (l << 3)) = ov;
        }
        stage_tile(Bt + k0, SS, Bs, w, l);
        __syncthreads();
        mfma_tile(As, Bs, acc, w, l);
        __syncthreads();
    }
    float* out = Out + ((size_t)b * SS + (size_t)qt * 128) * SH + nt * 128;
    int wr = (w >> 1) * 64, wc = (w & 1) * 64, g = l >> 4, c = l & 15;
#pragma unroll
    for (int m = 0; m < 4; m++)
#pragma unroll
        for (int j = 0; j < 4; j++) {
            size_t ro = (size_t)(wr + m * 16 + g * 4 + j) * SH;
#pragma unroll
            for (int n = 0; n < 4; n++)
                out[ro + wc + n * 16 + c] = acc[m][n][j];
        }
}

// ---------------- launch ---------------------------------------------------
extern "C" void kernel_launch(void* const* d_in, const int* in_sizes, int n_in,
                              void* d_out, int out_size, void* d_ws, size_t ws_size,
                              hipStream_t stream) {
    const float* x = (const float*)d_in[0];
    const int* amask = (const int*)d_in[1];
    const float* wq = (const float*)d_in[2];
    const float* wk = (const float*)d_in[3];
    const float* wv = (const float*)d_in[4];
    float* out = (float*)d_out;

    const size_t SZQ = (size_t)MTOT * SH * 2;       // 33,554,432 B per bf16 [16384][1024]
    const size_t SZSTAT = (size_t)MTOT * 32 * 4;    // 2,097,152 B
    char* ws = (char*)d_ws;
    u16* Q   = (u16*)(ws);
    u16* Kb  = (u16*)(ws + SZQ);
    u16* V   = (u16*)(ws + 2 * SZQ);
    u16* Vt  = (u16*)(ws + 3 * SZQ);
    float* mb = (float*)(ws + 4 * SZQ);
    float* lb = (float*)(ws + 4 * SZQ + SZSTAT);
    float* sb = (float*)(ws + 4 * SZQ + 2 * SZSTAT);
    u16* P   = (u16*)(ws + 4 * SZQ + 3 * SZSTAT);   // 67 MB region
    u16* xb  = P;                                   // x_bf16 overlaps P (dead before scores)
    u16* wb  = P + (size_t)MTOT * SH;               // w_bf16 after x_bf16

    cvt_f32_bf16<<<8192, 256, 0, stream>>>(x, xb, MTOT * SH / 8);
    cvt_f32_bf16<<<512, 256, 0, stream>>>(wq, wb, SH * SH / 8);
    cvt_f32_bf16<<<512, 256, 0, stream>>>(wk, wb + (size_t)SH * SH, SH * SH / 8);
    cvt_f32_bf16<<<512, 256, 0, stream>>>(wv, wb + (size_t)2 * SH * SH, SH * SH / 8);

    gemm_qkv<<<dim3(128, 24), 256, 0, stream>>>(xb, wb, Q, Kb, V);
    transpose_v<<<dim3(32, 16, 8), 256, 0, stream>>>(V, Vt);
    gemm_scores<<<dim3(136, 8), 256, 0, stream>>>(Q, Kb, P, mb, lb, amask);
    combine_stats<<<4096, 256, 0, stream>>>(mb, lb, sb, amask);
    gemm_pv<<<dim3(128, 8), 256, 0, stream>>>(P, Vt, sb, out);
}

// Round 6
// 424.018 us; speedup vs baseline: 1.0200x; 1.0200x over previous
//
#include <hip/hip_runtime.h>
#include <stdint.h>

typedef unsigned short u16;
typedef __bf16 bf16x8 __attribute__((ext_vector_type(8)));
typedef float f32x4 __attribute__((ext_vector_type(4)));
typedef u16 ushort8 __attribute__((ext_vector_type(8)));

#define SB 8
#define SS 2048
#define SH 1024
#define MTOT (SB*SS)
#define LOG2E 1.44269504088896f
#define NEG_INF (-__builtin_inff())

typedef __attribute__((address_space(3))) void lds_void;
typedef __attribute__((address_space(1))) const void gbl_void;

__device__ __forceinline__ float bf2f(u16 v) {
    union { unsigned int u; float f; } x; x.u = ((unsigned int)v) << 16; return x.f;
}
__device__ __forceinline__ u16 f2bf(float f) {
    unsigned int u = __builtin_bit_cast(unsigned int, f);
    u += 0x7fffu + ((u >> 16) & 1u);
    return (u16)(u >> 16);
}

// ---------------- fp32 -> bf16 conversion (vectorized, 8 elems/thread) ----
__global__ void cvt_f32_bf16(const float* __restrict__ in, u16* __restrict__ out, int n8) {
    int i = blockIdx.x * 256 + threadIdx.x;
    if (i >= n8) return;
    const float4* p = (const float4*)(in + (size_t)i * 8);
    float4 a = p[0], b = p[1];
    ushort8 r;
    r[0] = f2bf(a.x); r[1] = f2bf(a.y); r[2] = f2bf(a.z); r[3] = f2bf(a.w);
    r[4] = f2bf(b.x); r[5] = f2bf(b.y); r[6] = f2bf(b.z); r[7] = f2bf(b.w);
    *(ushort8*)(out + (size_t)i * 8) = r;
}

// ---------------- m97-style building blocks (used by scores/pv) -----------
__device__ __forceinline__ void stage_tile(const u16* __restrict__ g, int ld,
                                           u16* lds, int w, int l) {
#pragma unroll
    for (int i = 0; i < 4; i++) {
        int chunk = i * 4 + w;
        int r = chunk * 8 + (l >> 3);
        int c = (l & 7) * 8;
        __builtin_amdgcn_global_load_lds(
            (gbl_void*)(g + (size_t)r * ld + c),
            (lds_void*)(lds + chunk * 512), 16, 0, 0);
    }
}

__device__ __forceinline__ void mfma_tile(const u16* As, const u16* Bs,
                                          f32x4 acc[4][4], int w, int l) {
    int wr = (w >> 1) * 64, wc = (w & 1) * 64;
    int lr = l & 15, lk = (l >> 4) * 8;
#pragma unroll
    for (int kk = 0; kk < 2; kk++) {
        bf16x8 af[4], bb[4];
#pragma unroll
        for (int m = 0; m < 4; m++)
            af[m] = *(const bf16x8*)(const void*)(As + (wr + m * 16 + lr) * 64 + kk * 32 + lk);
#pragma unroll
        for (int n = 0; n < 4; n++)
            bb[n] = *(const bf16x8*)(const void*)(Bs + (wc + n * 16 + lr) * 64 + kk * 32 + lk);
#pragma unroll
        for (int m = 0; m < 4; m++)
#pragma unroll
            for (int n = 0; n < 4; n++)
                acc[m][n] = __builtin_amdgcn_mfma_f32_16x16x32_bf16(af[m], bb[n], acc[m][n], 0, 0, 0);
    }
}

// ================= QKV: 256x256 tile, BK=64, 8-phase pipeline =============
// C = X @ Wcat^T.  Wcat = [wq;wk;wv] rows (3072 x 1024), both operands K-major.
// 8 waves (2M x 4N), per-wave 128x64 output. LDS 128 KiB (A/B double-buffered).
// Swizzle: LDS(r,c) holds global (r, c ^ ((r&7)<<3)) -> 2-way max bank alias.
#define QNT 16   // K/64

#define STAGE8(gbase, ld, bufidx, h, t) do {                                          \
    const u16* _g = (gbase) + ((size_t)((h)*128 + srow)) * (ld) + (size_t)(t)*64 + scol; \
    u16* _d = &lds4[bufidx][((h)*128 + (w << 3)) * 64];                               \
    __builtin_amdgcn_global_load_lds((gbl_void*)_g, (lds_void*)_d, 16, 0, 0);         \
    __builtin_amdgcn_global_load_lds((gbl_void*)(_g + (size_t)64*(ld)),               \
                                     (lds_void*)(_d + 64*64), 16, 0, 0);              \
} while (0)

#define LDA8(mf, kkv) (*(const bf16x8*)(const void*)(Ab + (wr + (mf)*16 + rrow)*64 + rk##kkv))
#define LDB8(nf, kkv) (*(const bf16x8*)(const void*)(Bb + (wc + (nf)*16 + rrow)*64 + rk##kkv))

#define MFMA_PAIR(mf, A0, A1)                                                          \
    acc[mf][0] = __builtin_amdgcn_mfma_f32_16x16x32_bf16(A0, b00, acc[mf][0], 0,0,0);  \
    acc[mf][0] = __builtin_amdgcn_mfma_f32_16x16x32_bf16(A1, b01, acc[mf][0], 0,0,0);  \
    acc[mf][1] = __builtin_amdgcn_mfma_f32_16x16x32_bf16(A0, b10, acc[mf][1], 0,0,0);  \
    acc[mf][1] = __builtin_amdgcn_mfma_f32_16x16x32_bf16(A1, b11, acc[mf][1], 0,0,0);  \
    acc[mf][2] = __builtin_amdgcn_mfma_f32_16x16x32_bf16(A0, b20, acc[mf][2], 0,0,0);  \
    acc[mf][2] = __builtin_amdgcn_mfma_f32_16x16x32_bf16(A1, b21, acc[mf][2], 0,0,0);  \
    acc[mf][3] = __builtin_amdgcn_mfma_f32_16x16x32_bf16(A0, b30, acc[mf][3], 0,0,0);  \
    acc[mf][3] = __builtin_amdgcn_mfma_f32_16x16x32_bf16(A1, b31, acc[mf][3], 0,0,0);

#define PH_BAR_MID()                       \
    __builtin_amdgcn_sched_barrier(0);     \
    __builtin_amdgcn_s_barrier();          \
    __builtin_amdgcn_sched_barrier(0);

#define PH_BAR_END()                       \
    __builtin_amdgcn_sched_barrier(0);     \
    __builtin_amdgcn_s_barrier();          \
    __builtin_amdgcn_sched_barrier(0);

__global__ __launch_bounds__(512, 2) void gemm_qkv8(
    const u16* __restrict__ X, const u16* __restrict__ W,
    u16* __restrict__ Q, u16* __restrict__ Kd, u16* __restrict__ Vd) {
    __shared__ u16 lds4[4][256 * 64];   // [0]=A p0 [1]=A p1 [2]=B p0 [3]=B p1

    int tid = threadIdx.x, w = tid >> 6, l = tid & 63;
    // XCD-aware remap: 768 blocks = 8 XCDs x 96 contiguous
    int bid = blockIdx.x;
    int wg = (bid & 7) * 96 + (bid >> 3);
    int mt = wg / 12, nb = wg % 12;

    const u16* gA = X + (size_t)mt * 256 * SH;
    const u16* gB = W + (size_t)nb * 256 * SH;

    // staging lane geometry
    int srow = (w << 3) + (l >> 3);                       // 0..63 per issue
    int scol = (((l & 7) ^ ((l >> 3) & 7)) << 3);         // pre-swizzled source col
    // read lane geometry
    int wr = (w >> 2) * 128, wc = (w & 3) * 64;
    int rrow = l & 15;
    int rk0 = (((l >> 4) ^ (l & 7)) << 3);                // kk=0 swizzled col
    int rk1 = (((4 + (l >> 4)) ^ (l & 7)) << 3);          // kk=1 swizzled col

    f32x4 acc[8][4];
#pragma unroll
    for (int m = 0; m < 8; m++)
#pragma unroll
        for (int n = 0; n < 4; n++) acc[m][n] = (f32x4){0.f, 0.f, 0.f, 0.f};

    // ---- prologue: A(0), B(0), B(1); wait A(0)+B(0) landed (leave B(1) 4 in flight)
    STAGE8(gA, SH, 0, 0, 0); STAGE8(gA, SH, 0, 1, 0);
    STAGE8(gB, SH, 2, 0, 0); STAGE8(gB, SH, 2, 1, 0);
    STAGE8(gB, SH, 3, 0, 1); STAGE8(gB, SH, 3, 1, 1);
    asm volatile("s_waitcnt vmcnt(4)" ::: "memory");
    __builtin_amdgcn_s_barrier();
    __builtin_amdgcn_sched_barrier(0);

    for (int t = 0; t < QNT; ++t) {
        const int p = t & 1;
        const u16* Ab = &lds4[p][0];
        const u16* Bb = &lds4[2 + p][0];

        // ---- phase 0: read all B-frags + A mf{0,1}; stage A0(t+1)
        bf16x8 b00 = LDB8(0, 0), b01 = LDB8(0, 1), b10 = LDB8(1, 0), b11 = LDB8(1, 1);
        bf16x8 b20 = LDB8(2, 0), b21 = LDB8(2, 1), b30 = LDB8(3, 0), b31 = LDB8(3, 1);
        {
            bf16x8 a00 = LDA8(0, 0), a01 = LDA8(0, 1), a10 = LDA8(1, 0), a11 = LDA8(1, 1);
            if (t + 1 < QNT) STAGE8(gA, SH, (t + 1) & 1, 0, t + 1);
            PH_BAR_MID();
            __builtin_amdgcn_s_setprio(1);
            MFMA_PAIR(0, a00, a01);
            MFMA_PAIR(1, a10, a11);
            __builtin_amdgcn_s_setprio(0);
            PH_BAR_END();
        }
        // ---- phase 1: A mf{2,3}; stage A1(t+1)
        {
            bf16x8 a00 = LDA8(2, 0), a01 = LDA8(2, 1), a10 = LDA8(3, 0), a11 = LDA8(3, 1);
            if (t + 1 < QNT) STAGE8(gA, SH, (t + 1) & 1, 1, t + 1);
            PH_BAR_MID();
            __builtin_amdgcn_s_setprio(1);
            MFMA_PAIR(2, a00, a01);
            MFMA_PAIR(3, a10, a11);
            __builtin_amdgcn_s_setprio(0);
            PH_BAR_END();
        }
        // ---- phase 2: A mf{4,5}; stage B0(t+2)
        {
            bf16x8 a00 = LDA8(4, 0), a01 = LDA8(4, 1), a10 = LDA8(5, 0), a11 = LDA8(5, 1);
            if (t + 2 < QNT) STAGE8(gB, SH, 2 + (t & 1), 0, t + 2);
            PH_BAR_MID();
            __builtin_amdgcn_s_setprio(1);
            MFMA_PAIR(4, a00, a01);
            MFMA_PAIR(5, a10, a11);
            __builtin_amdgcn_s_setprio(0);
            PH_BAR_END();
        }
        // ---- phase 3: A mf{6,7}; stage B1(t+2); vmcnt gate (once per K-tile)
        {
            bf16x8 a00 = LDA8(6, 0), a01 = LDA8(6, 1), a10 = LDA8(7, 0), a11 = LDA8(7, 1);
            if (t + 2 < QNT) STAGE8(gB, SH, 2 + (t & 1), 1, t + 2);
            if (t + 2 < QNT)      asm volatile("s_waitcnt vmcnt(4)" ::: "memory");
            else if (t + 1 < QNT) asm volatile("s_waitcnt vmcnt(0)" ::: "memory");
            PH_BAR_MID();
            __builtin_amdgcn_s_setprio(1);
            MFMA_PAIR(6, a00, a01);
            MFMA_PAIR(7, a10, a11);
            __builtin_amdgcn_s_setprio(0);
            PH_BAR_END();
        }
    }

    // ---- epilogue: write 128x64 per wave
    u16* outp = (nb < 4 ? Q : (nb < 8 ? Kd : Vd));
    int colbase = (nb & 3) * 256 + wc;
    size_t rowbase = (size_t)mt * 256 + wr;
    int g = l >> 4, c = l & 15;
#pragma unroll
    for (int mf = 0; mf < 8; mf++)
#pragma unroll
        for (int j = 0; j < 4; j++) {
            size_t ro = (rowbase + mf * 16 + g * 4 + j) * SH;
#pragma unroll
            for (int nf = 0; nf < 4; nf++)
                outp[ro + colbase + nf * 16 + c] = f2bf(acc[mf][nf][j]);
        }
}

// ---------------- V transpose: Vt[b][o][s] = V[b*S+s][o] ------------------
__global__ void transpose_v(const u16* __restrict__ V, u16* __restrict__ Vt) {
    __shared__ u16 t[64][80];
    int s0 = blockIdx.x * 64, o0 = blockIdx.y * 64, b = blockIdx.z;
    const u16* src = V + (size_t)b * SS * SH;
    u16* dst = Vt + (size_t)b * SH * SS;
    int tid = threadIdx.x;
#pragma unroll
    for (int it = 0; it < 2; it++) {
        int idx = it * 256 + tid;
        int r = idx >> 3, gq = idx & 7;
        *(ushort8*)&t[r][gq * 8] = *(const ushort8*)&src[(size_t)(s0 + r) * SH + o0 + gq * 8];
    }
    __syncthreads();
#pragma unroll
    for (int it = 0; it < 2; it++) {
        int idx = it * 256 + tid;
        int rr = idx >> 3, cc = idx & 7;
        ushort8 v;
#pragma unroll
        for (int e = 0; e < 8; e++) v[e] = t[cc * 8 + e][rr];
        *(ushort8*)&dst[(size_t)(o0 + rr) * SS + s0 + cc * 8] = v;
    }
}

// ---------------- Scores: S = QK^T/32, lower-tri tiles; write Ptilde + stats
__global__ __launch_bounds__(256, 2) void gemm_scores(
    const u16* __restrict__ Q, const u16* __restrict__ K,
    u16* __restrict__ P, float* __restrict__ mb, float* __restrict__ lb,
    const int* __restrict__ amask) {
    __shared__ u16 As[128 * 64];
    __shared__ u16 Bs[128 * 64];
    int tid = threadIdx.x, w = tid >> 6, l = tid & 63;
    int b = blockIdx.y, t = blockIdx.x;
    int qt = (int)((sqrtf(8.f * (float)t + 1.f) - 1.f) * 0.5f);
    while ((qt + 1) * (qt + 2) / 2 <= t) qt++;
    while (qt * (qt + 1) / 2 > t) qt--;
    int kt = t - qt * (qt + 1) / 2;
    const u16* A = Q + ((size_t)b * SS + (size_t)qt * 128) * SH;
    const u16* Bt = K + ((size_t)b * SS + (size_t)kt * 128) * SH;
    f32x4 acc[4][4];
#pragma unroll
    for (int m = 0; m < 4; m++)
#pragma unroll
        for (int n = 0; n < 4; n++) acc[m][n] = (f32x4){0.f, 0.f, 0.f, 0.f};
    for (int k0 = 0; k0 < SH; k0 += 64) {
        stage_tile(A + k0, SH, As, w, l);
        stage_tile(Bt + k0, SH, Bs, w, l);
        __syncthreads();
        mfma_tile(As, Bs, acc, w, l);
        __syncthreads();
    }
    int wr = (w >> 1) * 64, wc = (w & 1) * 64, g = l >> 4, c = l & 15;
    int q0 = qt * 128 + wr;
    int k0w = kt * 128 + wc;
    int cglob = kt * 2 + (w & 1);
    u16* Pb = P + (size_t)b * SS * SS;
    float* mbb = mb + (size_t)b * SS * 32;
    float* lbb = lb + (size_t)b * SS * 32;
    int kg[4], kv[4];
#pragma unroll
    for (int n = 0; n < 4; n++) { kg[n] = k0w + n * 16 + c; kv[n] = amask[b * SS + kg[n]]; }
#pragma unroll
    for (int m = 0; m < 4; m++) {
#pragma unroll
        for (int j = 0; j < 4; j++) {
            int qg = q0 + m * 16 + g * 4 + j;
            float sv[4]; float mx = NEG_INF;
#pragma unroll
            for (int n = 0; n < 4; n++) {
                float s = acc[m][n][j] * 0.03125f;
                bool ok = (kg[n] <= qg) && (kv[n] != 0);
                s = ok ? s : NEG_INF;
                sv[n] = s; mx = fmaxf(mx, s);
            }
#pragma unroll
            for (int d = 1; d < 16; d <<= 1) mx = fmaxf(mx, __shfl_xor(mx, d, 64));
            float ls = 0.f;
#pragma unroll
            for (int n = 0; n < 4; n++) {
                float pv = (sv[n] == NEG_INF) ? 0.f : exp2f((sv[n] - mx) * LOG2E);
                sv[n] = pv; ls += pv;
            }
#pragma unroll
            for (int d = 1; d < 16; d <<= 1) ls += __shfl_xor(ls, d, 64);
            size_t prow = (size_t)qg * SS;
#pragma unroll
            for (int n = 0; n < 4; n++) Pb[prow + kg[n]] = f2bf(sv[n]);
            if (c == 0) { mbb[(size_t)qg * 32 + cglob] = mx; lbb[(size_t)qg * 32 + cglob] = ls; }
        }
    }
}

// ---------------- Combine stats -> per-chunk scale ------------------------
__global__ void combine_stats(const float* __restrict__ mb, const float* __restrict__ lb,
                              float* __restrict__ sb, const int* __restrict__ amask) {
    int row = blockIdx.x * 4 + (threadIdx.x >> 6);
    int l = threadIdx.x & 63;
    int b = row >> 11, q = row & 2047;
    int cmax = q >> 6;
    float mc = NEG_INF, lc = 0.f;
    if (l < 32 && l <= cmax) { mc = mb[(size_t)row * 32 + l]; lc = lb[(size_t)row * 32 + l]; }
    float mstar = mc;
#pragma unroll
    for (int d = 1; d < 64; d <<= 1) mstar = fmaxf(mstar, __shfl_xor(mstar, d, 64));
    float term = (mc > NEG_INF) ? lc * exp2f((mc - mstar) * LOG2E) : 0.f;
    float L = term;
#pragma unroll
    for (int d = 1; d < 64; d <<= 1) L += __shfl_xor(L, d, 64);
    int qv = amask[b * SS + q];
    float inv = (qv != 0 && L > 0.f) ? 1.0f / L : 0.f;
    float sc = (mc > NEG_INF) ? exp2f((mc - mstar) * LOG2E) * inv : 0.f;
    if (l < 32) sb[(size_t)row * 32 + l] = sc;
}

// ---------------- PV: O = (scale*Ptilde) @ Vt^T, fp32 out, causal K-bound -
__global__ __launch_bounds__(256, 2) void gemm_pv(
    const u16* __restrict__ P, const u16* __restrict__ Vt,
    const float* __restrict__ sb, float* __restrict__ Out) {
    __shared__ u16 As[128 * 64];
    __shared__ u16 Bs[128 * 64];
    int tid = threadIdx.x, w = tid >> 6, l = tid & 63;
    int b = blockIdx.y;
    int qt = blockIdx.x >> 3, nt = blockIdx.x & 7;
    const u16* Ab = P + (size_t)b * SS * SS + (size_t)qt * 128 * SS;
    const u16* Bt = Vt + (size_t)b * SH * SS + (size_t)nt * 128 * SS;
    const float* scl = sb + ((size_t)b * SS + (size_t)qt * 128) * 32;
    int ksize = (qt + 1) * 128;
    f32x4 acc[4][4];
#pragma unroll
    for (int m = 0; m < 4; m++)
#pragma unroll
        for (int n = 0; n < 4; n++) acc[m][n] = (f32x4){0.f, 0.f, 0.f, 0.f};
    for (int k0 = 0; k0 < ksize; k0 += 64) {
#pragma unroll
        for (int i = 0; i < 4; i++) {
            int chunk = i * 4 + w;
            int r = chunk * 8 + (l >> 3);
            int cc = (l & 7) * 8;
            ushort8 pv = *(const ushort8*)(Ab + (size_t)r * SS + k0 + cc);
            float sc = scl[r * 32 + (k0 >> 6)];
            ushort8 ov;
#pragma unroll
            for (int e = 0; e < 8; e++) ov[e] = f2bf(bf2f(pv[e]) * sc);
            *(ushort8*)(As + chunk * 512 + (l << 3)) = ov;
        }
        stage_tile(Bt + k0, SS, Bs, w, l);
        __syncthreads();
        mfma_tile(As, Bs, acc, w, l);
        __syncthreads();
    }
    float* out = Out + ((size_t)b * SS + (size_t)qt * 128) * SH + nt * 128;
    int wr = (w >> 1) * 64, wc = (w & 1) * 64, g = l >> 4, c = l & 15;
#pragma unroll
    for (int m = 0; m < 4; m++)
#pragma unroll
        for (int j = 0; j < 4; j++) {
            size_t ro = (size_t)(wr + m * 16 + g * 4 + j) * SH;
#pragma unroll
            for (int n = 0; n < 4; n++)
                out[ro + wc + n * 16 + c] = acc[m][n][j];
        }
}

// ---------------- launch ---------------------------------------------------
extern "C" void kernel_launch(void* const* d_in, const int* in_sizes, int n_in,
                              void* d_out, int out_size, void* d_ws, size_t ws_size,
                              hipStream_t stream) {
    const float* x = (const float*)d_in[0];
    const int* amask = (const int*)d_in[1];
    const float* wq = (const float*)d_in[2];
    const float* wk = (const float*)d_in[3];
    const float* wv = (const float*)d_in[4];
    float* out = (float*)d_out;

    const size_t SZQ = (size_t)MTOT * SH * 2;
    const size_t SZSTAT = (size_t)MTOT * 32 * 4;
    char* ws = (char*)d_ws;
    u16* Q   = (u16*)(ws);
    u16* Kb  = (u16*)(ws + SZQ);
    u16* V   = (u16*)(ws + 2 * SZQ);
    u16* Vt  = (u16*)(ws + 3 * SZQ);
    float* mb = (float*)(ws + 4 * SZQ);
    float* lb = (float*)(ws + 4 * SZQ + SZSTAT);
    float* sb = (float*)(ws + 4 * SZQ + 2 * SZSTAT);
    u16* P   = (u16*)(ws + 4 * SZQ + 3 * SZSTAT);
    u16* xb  = P;                                   // x_bf16 overlaps P (dead before scores)
    u16* wb  = P + (size_t)MTOT * SH;               // w_bf16 after x_bf16

    cvt_f32_bf16<<<8192, 256, 0, stream>>>(x, xb, MTOT * SH / 8);
    cvt_f32_bf16<<<512, 256, 0, stream>>>(wq, wb, SH * SH / 8);
    cvt_f32_bf16<<<512, 256, 0, stream>>>(wk, wb + (size_t)SH * SH, SH * SH / 8);
    cvt_f32_bf16<<<512, 256, 0, stream>>>(wv, wb + (size_t)2 * SH * SH, SH * SH / 8);

    gemm_qkv8<<<768, 512, 0, stream>>>(xb, wb, Q, Kb, V);
    transpose_v<<<dim3(32, 16, 8), 256, 0, stream>>>(V, Vt);
    gemm_scores<<<dim3(136, 8), 256, 0, stream>>>(Q, Kb, P, mb, lb, amask);
    combine_stats<<<4096, 256, 0, stream>>>(mb, lb, sb, amask);
    gemm_pv<<<dim3(128, 8), 256, 0, stream>>>(P, Vt, sb, out);
}

// Round 7
// 395.228 us; speedup vs baseline: 1.0943x; 1.0728x over previous
//
#include <hip/hip_runtime.h>
#include <stdint.h>

typedef unsigned short u16;
typedef __bf16 bf16x8 __attribute__((ext_vector_type(8)));
typedef float f32x4 __attribute__((ext_vector_type(4)));
typedef u16 ushort8 __attribute__((ext_vector_type(8)));

#define SB 8
#define SS 2048
#define SH 1024
#define MTOT (SB*SS)
#define LOG2E 1.44269504088896f
#define SEXP (1.44269504088896f/32.f)   // exp(s/32) = exp2(s*SEXP)
#define NEG_INF (-__builtin_inff())

typedef __attribute__((address_space(3))) void lds_void;
typedef __attribute__((address_space(1))) const void gbl_void;

__device__ __forceinline__ float bf2f(u16 v) {
    union { unsigned int u; float f; } x; x.u = ((unsigned int)v) << 16; return x.f;
}
__device__ __forceinline__ u16 f2bf(float f) {
    unsigned int u = __builtin_bit_cast(unsigned int, f);
    u += 0x7fffu + ((u >> 16) & 1u);
    return (u16)(u >> 16);
}

// ---------------- fp32 -> bf16 conversion (vectorized, 8 elems/thread) ----
__global__ void cvt_f32_bf16(const float* __restrict__ in, u16* __restrict__ out, int n8) {
    int i = blockIdx.x * 256 + threadIdx.x;
    if (i >= n8) return;
    const float4* p = (const float4*)(in + (size_t)i * 8);
    float4 a = p[0], b = p[1];
    ushort8 r;
    r[0] = f2bf(a.x); r[1] = f2bf(a.y); r[2] = f2bf(a.z); r[3] = f2bf(a.w);
    r[4] = f2bf(b.x); r[5] = f2bf(b.y); r[6] = f2bf(b.z); r[7] = f2bf(b.w);
    *(ushort8*)(out + (size_t)i * 8) = r;
}

// ---------------- m97-style building blocks (scores/pv) -------------------
__device__ __forceinline__ void stage_tile(const u16* __restrict__ g, int ld,
                                           u16* lds, int w, int l) {
#pragma unroll
    for (int i = 0; i < 4; i++) {
        int chunk = i * 4 + w;
        int r = chunk * 8 + (l >> 3);
        int c = (l & 7) * 8;
        __builtin_amdgcn_global_load_lds(
            (gbl_void*)(g + (size_t)r * ld + c),
            (lds_void*)(lds + chunk * 512), 16, 0, 0);
    }
}

__device__ __forceinline__ void mfma_tile(const u16* As, const u16* Bs,
                                          f32x4 acc[4][4], int w, int l) {
    int wr = (w >> 1) * 64, wc = (w & 1) * 64;
    int lr = l & 15, lk = (l >> 4) * 8;
#pragma unroll
    for (int kk = 0; kk < 2; kk++) {
        bf16x8 af[4], bb[4];
#pragma unroll
        for (int m = 0; m < 4; m++)
            af[m] = *(const bf16x8*)(const void*)(As + (wr + m * 16 + lr) * 64 + kk * 32 + lk);
#pragma unroll
        for (int n = 0; n < 4; n++)
            bb[n] = *(const bf16x8*)(const void*)(Bs + (wc + n * 16 + lr) * 64 + kk * 32 + lk);
#pragma unroll
        for (int m = 0; m < 4; m++)
#pragma unroll
            for (int n = 0; n < 4; n++)
                acc[m][n] = __builtin_amdgcn_mfma_f32_16x16x32_bf16(af[m], bb[n], acc[m][n], 0, 0, 0);
    }
}

// ================= QKV: 256x256 tile, BK=64, 8-phase pipeline (verified r6)
#define QNT 16   // K/64

#define STAGE8(gbase, ld, bufidx, h, t) do {                                          \
    const u16* _g = (gbase) + ((size_t)((h)*128 + srow)) * (ld) + (size_t)(t)*64 + scol; \
    u16* _d = &lds4[bufidx][((h)*128 + (w << 3)) * 64];                               \
    __builtin_amdgcn_global_load_lds((gbl_void*)_g, (lds_void*)_d, 16, 0, 0);         \
    __builtin_amdgcn_global_load_lds((gbl_void*)(_g + (size_t)64*(ld)),               \
                                     (lds_void*)(_d + 64*64), 16, 0, 0);              \
} while (0)

#define LDA8(mf, kkv) (*(const bf16x8*)(const void*)(Ab + (wr + (mf)*16 + rrow)*64 + rk##kkv))
#define LDB8(nf, kkv) (*(const bf16x8*)(const void*)(Bb + (wc + (nf)*16 + rrow)*64 + rk##kkv))

#define MFMA_PAIR(mf, A0, A1)                                                          \
    acc[mf][0] = __builtin_amdgcn_mfma_f32_16x16x32_bf16(A0, b00, acc[mf][0], 0,0,0);  \
    acc[mf][0] = __builtin_amdgcn_mfma_f32_16x16x32_bf16(A1, b01, acc[mf][0], 0,0,0);  \
    acc[mf][1] = __builtin_amdgcn_mfma_f32_16x16x32_bf16(A0, b10, acc[mf][1], 0,0,0);  \
    acc[mf][1] = __builtin_amdgcn_mfma_f32_16x16x32_bf16(A1, b11, acc[mf][1], 0,0,0);  \
    acc[mf][2] = __builtin_amdgcn_mfma_f32_16x16x32_bf16(A0, b20, acc[mf][2], 0,0,0);  \
    acc[mf][2] = __builtin_amdgcn_mfma_f32_16x16x32_bf16(A1, b21, acc[mf][2], 0,0,0);  \
    acc[mf][3] = __builtin_amdgcn_mfma_f32_16x16x32_bf16(A0, b30, acc[mf][3], 0,0,0);  \
    acc[mf][3] = __builtin_amdgcn_mfma_f32_16x16x32_bf16(A1, b31, acc[mf][3], 0,0,0);

#define PH_BAR_MID()                       \
    __builtin_amdgcn_sched_barrier(0);     \
    __builtin_amdgcn_s_barrier();          \
    __builtin_amdgcn_sched_barrier(0);

#define PH_BAR_END()                       \
    __builtin_amdgcn_sched_barrier(0);     \
    __builtin_amdgcn_s_barrier();          \
    __builtin_amdgcn_sched_barrier(0);

__global__ __launch_bounds__(512, 2) void gemm_qkv8(
    const u16* __restrict__ X, const u16* __restrict__ W,
    u16* __restrict__ Q, u16* __restrict__ Kd, u16* __restrict__ Vd) {
    __shared__ u16 lds4[4][256 * 64];

    int tid = threadIdx.x, w = tid >> 6, l = tid & 63;
    int bid = blockIdx.x;
    int wg = (bid & 7) * 96 + (bid >> 3);
    int mt = wg / 12, nb = wg % 12;

    const u16* gA = X + (size_t)mt * 256 * SH;
    const u16* gB = W + (size_t)nb * 256 * SH;

    int srow = (w << 3) + (l >> 3);
    int scol = (((l & 7) ^ ((l >> 3) & 7)) << 3);
    int wr = (w >> 2) * 128, wc = (w & 3) * 64;
    int rrow = l & 15;
    int rk0 = (((l >> 4) ^ (l & 7)) << 3);
    int rk1 = (((4 + (l >> 4)) ^ (l & 7)) << 3);

    f32x4 acc[8][4];
#pragma unroll
    for (int m = 0; m < 8; m++)
#pragma unroll
        for (int n = 0; n < 4; n++) acc[m][n] = (f32x4){0.f, 0.f, 0.f, 0.f};

    STAGE8(gA, SH, 0, 0, 0); STAGE8(gA, SH, 0, 1, 0);
    STAGE8(gB, SH, 2, 0, 0); STAGE8(gB, SH, 2, 1, 0);
    STAGE8(gB, SH, 3, 0, 1); STAGE8(gB, SH, 3, 1, 1);
    asm volatile("s_waitcnt vmcnt(4)" ::: "memory");
    __builtin_amdgcn_s_barrier();
    __builtin_amdgcn_sched_barrier(0);

    for (int t = 0; t < QNT; ++t) {
        const int p = t & 1;
        const u16* Ab = &lds4[p][0];
        const u16* Bb = &lds4[2 + p][0];

        bf16x8 b00 = LDB8(0, 0), b01 = LDB8(0, 1), b10 = LDB8(1, 0), b11 = LDB8(1, 1);
        bf16x8 b20 = LDB8(2, 0), b21 = LDB8(2, 1), b30 = LDB8(3, 0), b31 = LDB8(3, 1);
        {
            bf16x8 a00 = LDA8(0, 0), a01 = LDA8(0, 1), a10 = LDA8(1, 0), a11 = LDA8(1, 1);
            if (t + 1 < QNT) STAGE8(gA, SH, (t + 1) & 1, 0, t + 1);
            PH_BAR_MID();
            __builtin_amdgcn_s_setprio(1);
            MFMA_PAIR(0, a00, a01);
            MFMA_PAIR(1, a10, a11);
            __builtin_amdgcn_s_setprio(0);
            PH_BAR_END();
        }
        {
            bf16x8 a00 = LDA8(2, 0), a01 = LDA8(2, 1), a10 = LDA8(3, 0), a11 = LDA8(3, 1);
            if (t + 1 < QNT) STAGE8(gA, SH, (t + 1) & 1, 1, t + 1);
            PH_BAR_MID();
            __builtin_amdgcn_s_setprio(1);
            MFMA_PAIR(2, a00, a01);
            MFMA_PAIR(3, a10, a11);
            __builtin_amdgcn_s_setprio(0);
            PH_BAR_END();
        }
        {
            bf16x8 a00 = LDA8(4, 0), a01 = LDA8(4, 1), a10 = LDA8(5, 0), a11 = LDA8(5, 1);
            if (t + 2 < QNT) STAGE8(gB, SH, 2 + (t & 1), 0, t + 2);
            PH_BAR_MID();
            __builtin_amdgcn_s_setprio(1);
            MFMA_PAIR(4, a00, a01);
            MFMA_PAIR(5, a10, a11);
            __builtin_amdgcn_s_setprio(0);
            PH_BAR_END();
        }
        {
            bf16x8 a00 = LDA8(6, 0), a01 = LDA8(6, 1), a10 = LDA8(7, 0), a11 = LDA8(7, 1);
            if (t + 2 < QNT) STAGE8(gB, SH, 2 + (t & 1), 1, t + 2);
            if (t + 2 < QNT)      asm volatile("s_waitcnt vmcnt(4)" ::: "memory");
            else if (t + 1 < QNT) asm volatile("s_waitcnt vmcnt(0)" ::: "memory");
            PH_BAR_MID();
            __builtin_amdgcn_s_setprio(1);
            MFMA_PAIR(6, a00, a01);
            MFMA_PAIR(7, a10, a11);
            __builtin_amdgcn_s_setprio(0);
            PH_BAR_END();
        }
    }

    u16* outp = (nb < 4 ? Q : (nb < 8 ? Kd : Vd));
    int colbase = (nb & 3) * 256 + wc;
    size_t rowbase = (size_t)mt * 256 + wr;
    int g = l >> 4, c = l & 15;
#pragma unroll
    for (int mf = 0; mf < 8; mf++)
#pragma unroll
        for (int j = 0; j < 4; j++) {
            size_t ro = (rowbase + mf * 16 + g * 4 + j) * SH;
#pragma unroll
            for (int nf = 0; nf < 4; nf++)
                outp[ro + colbase + nf * 16 + c] = f2bf(acc[mf][nf][j]);
        }
}

// ---------------- V transpose: Vt[b][o][s] = V[b*S+s][o] ------------------
__global__ void transpose_v(const u16* __restrict__ V, u16* __restrict__ Vt) {
    __shared__ u16 t[64][80];
    int s0 = blockIdx.x * 64, o0 = blockIdx.y * 64, b = blockIdx.z;
    const u16* src = V + (size_t)b * SS * SH;
    u16* dst = Vt + (size_t)b * SH * SS;
    int tid = threadIdx.x;
#pragma unroll
    for (int it = 0; it < 2; it++) {
        int idx = it * 256 + tid;
        int r = idx >> 3, gq = idx & 7;
        *(ushort8*)&t[r][gq * 8] = *(const ushort8*)&src[(size_t)(s0 + r) * SH + o0 + gq * 8];
    }
    __syncthreads();
#pragma unroll
    for (int it = 0; it < 2; it++) {
        int idx = it * 256 + tid;
        int rr = idx >> 3, cc = idx & 7;
        ushort8 v;
#pragma unroll
        for (int e = 0; e < 8; e++) v[e] = t[cc * 8 + e][rr];
        *(ushort8*)&dst[(size_t)(o0 + rr) * SS + s0 + cc * 8] = v;
    }
}

// ---------------- Scores: Ptilde = exp(qk/32) direct (no max), + chunk sums
__global__ __launch_bounds__(256, 2) void gemm_scores(
    const u16* __restrict__ Q, const u16* __restrict__ K,
    u16* __restrict__ P, float* __restrict__ lb,
    const int* __restrict__ amask) {
    __shared__ u16 As[128 * 64];
    __shared__ u16 Bs[128 * 64];
    int tid = threadIdx.x, w = tid >> 6, l = tid & 63;
    int b = blockIdx.y, t = blockIdx.x;
    int qt = (int)((sqrtf(8.f * (float)t + 1.f) - 1.f) * 0.5f);
    while ((qt + 1) * (qt + 2) / 2 <= t) qt++;
    while (qt * (qt + 1) / 2 > t) qt--;
    int kt = t - qt * (qt + 1) / 2;
    const u16* A = Q + ((size_t)b * SS + (size_t)qt * 128) * SH;
    const u16* Bt = K + ((size_t)b * SS + (size_t)kt * 128) * SH;
    f32x4 acc[4][4];
#pragma unroll
    for (int m = 0; m < 4; m++)
#pragma unroll
        for (int n = 0; n < 4; n++) acc[m][n] = (f32x4){0.f, 0.f, 0.f, 0.f};
    for (int k0 = 0; k0 < SH; k0 += 64) {
        stage_tile(A + k0, SH, As, w, l);
        stage_tile(Bt + k0, SH, Bs, w, l);
        __syncthreads();
        mfma_tile(As, Bs, acc, w, l);
        __syncthreads();
    }
    int wr = (w >> 1) * 64, wc = (w & 1) * 64, g = l >> 4, c = l & 15;
    int q0 = qt * 128 + wr;
    int k0w = kt * 128 + wc;
    int cglob = kt * 2 + (w & 1);
    u16* Pb = P + (size_t)b * SS * SS;
    float* lbb = lb + (size_t)b * SS * 32;
    int kg[4], kv[4];
#pragma unroll
    for (int n = 0; n < 4; n++) { kg[n] = k0w + n * 16 + c; kv[n] = amask[b * SS + kg[n]]; }
#pragma unroll
    for (int m = 0; m < 4; m++) {
#pragma unroll
        for (int j = 0; j < 4; j++) {
            int qg = q0 + m * 16 + g * 4 + j;
            float sv[4]; float ls = 0.f;
#pragma unroll
            for (int n = 0; n < 4; n++) {
                bool ok = (kg[n] <= qg) && (kv[n] != 0);
                float p = ok ? exp2f(acc[m][n][j] * SEXP) : 0.f;
                sv[n] = p; ls += p;
            }
#pragma unroll
            for (int d = 1; d < 16; d <<= 1) ls += __shfl_xor(ls, d, 64);
            size_t prow = (size_t)qg * SS;
#pragma unroll
            for (int n = 0; n < 4; n++) Pb[prow + kg[n]] = f2bf(sv[n]);
            if (c == 0) lbb[(size_t)qg * 32 + cglob] = ls;
        }
    }
}

// ---------------- Combine chunk sums -> per-row 1/L -----------------------
__global__ void combine_inv(const float* __restrict__ lb,
                            float* __restrict__ sb, const int* __restrict__ amask) {
    int row = blockIdx.x * 4 + (threadIdx.x >> 6);
    int l = threadIdx.x & 63;
    int b = row >> 11, q = row & 2047;
    int cmax = q >> 6;
    float L = (l < 32 && l <= cmax) ? lb[(size_t)row * 32 + l] : 0.f;
#pragma unroll
    for (int d = 1; d < 64; d <<= 1) L += __shfl_xor(L, d, 64);
    if (l == 0) {
        int qv = amask[b * SS + q];
        sb[row] = (qv != 0 && L > 0.f) ? 1.0f / L : 0.f;
    }
}

// ---------------- PV: O = (Ptilde @ Vt^T) * inv[row], pure gload_lds ------
__global__ __launch_bounds__(256, 2) void gemm_pv(
    const u16* __restrict__ P, const u16* __restrict__ Vt,
    const float* __restrict__ sb, float* __restrict__ Out) {
    __shared__ u16 As[128 * 64];
    __shared__ u16 Bs[128 * 64];
    int tid = threadIdx.x, w = tid >> 6, l = tid & 63;
    int b = blockIdx.y;
    int qt = blockIdx.x >> 3, nt = blockIdx.x & 7;
    const u16* Ab = P + (size_t)b * SS * SS + (size_t)qt * 128 * SS;
    const u16* Bt = Vt + (size_t)b * SH * SS + (size_t)nt * 128 * SS;
    int ksize = (qt + 1) * 128;
    f32x4 acc[4][4];
#pragma unroll
    for (int m = 0; m < 4; m++)
#pragma unroll
        for (int n = 0; n < 4; n++) acc[m][n] = (f32x4){0.f, 0.f, 0.f, 0.f};
    for (int k0 = 0; k0 < ksize; k0 += 64) {
        stage_tile(Ab + k0, SS, As, w, l);
        stage_tile(Bt + k0, SS, Bs, w, l);
        __syncthreads();
        mfma_tile(As, Bs, acc, w, l);
        __syncthreads();
    }
    const float* sbq = sb + (size_t)b * SS + (size_t)qt * 128;
    float* out = Out + ((size_t)b * SS + (size_t)qt * 128) * SH + nt * 128;
    int wr = (w >> 1) * 64, wc = (w & 1) * 64, g = l >> 4, c = l & 15;
#pragma unroll
    for (int m = 0; m < 4; m++)
#pragma unroll
        for (int j = 0; j < 4; j++) {
            int row = wr + m * 16 + g * 4 + j;
            float scl = sbq[row];
            size_t ro = (size_t)row * SH;
#pragma unroll
            for (int n = 0; n < 4; n++)
                out[ro + wc + n * 16 + c] = acc[m][n][j] * scl;
        }
}

// ---------------- launch ---------------------------------------------------
extern "C" void kernel_launch(void* const* d_in, const int* in_sizes, int n_in,
                              void* d_out, int out_size, void* d_ws, size_t ws_size,
                              hipStream_t stream) {
    const float* x = (const float*)d_in[0];
    const int* amask = (const int*)d_in[1];
    const float* wq = (const float*)d_in[2];
    const float* wk = (const float*)d_in[3];
    const float* wv = (const float*)d_in[4];
    float* out = (float*)d_out;

    const size_t SZQ = (size_t)MTOT * SH * 2;
    const size_t SZSTAT = (size_t)MTOT * 32 * 4;
    char* ws = (char*)d_ws;
    u16* Q   = (u16*)(ws);
    u16* Kb  = (u16*)(ws + SZQ);
    u16* V   = (u16*)(ws + 2 * SZQ);
    u16* Vt  = (u16*)(ws + 3 * SZQ);
    float* lb = (float*)(ws + 4 * SZQ);
    float* sb = (float*)(ws + 4 * SZQ + SZSTAT);          // MTOT floats
    u16* P   = (u16*)(ws + 4 * SZQ + 3 * SZSTAT);
    u16* xb  = P;                                   // x_bf16 overlaps P (dead before scores)
    u16* wb  = P + (size_t)MTOT * SH;               // w_bf16 after x_bf16

    cvt_f32_bf16<<<8192, 256, 0, stream>>>(x, xb, MTOT * SH / 8);
    cvt_f32_bf16<<<512, 256, 0, stream>>>(wq, wb, SH * SH / 8);
    cvt_f32_bf16<<<512, 256, 0, stream>>>(wk, wb + (size_t)SH * SH, SH * SH / 8);
    cvt_f32_bf16<<<512, 256, 0, stream>>>(wv, wb + (size_t)2 * SH * SH, SH * SH / 8);

    gemm_qkv8<<<768, 512, 0, stream>>>(xb, wb, Q, Kb, V);
    transpose_v<<<dim3(32, 16, 8), 256, 0, stream>>>(V, Vt);
    gemm_scores<<<dim3(136, 8), 256, 0, stream>>>(Q, Kb, P, lb, amask);
    combine_inv<<<4096, 256, 0, stream>>>(lb, sb, amask);
    gemm_pv<<<dim3(128, 8), 256, 0, stream>>>(P, Vt, sb, out);
}

// Round 8
// 348.320 us; speedup vs baseline: 1.2417x; 1.1347x over previous
//
#include <hip/hip_runtime.h>
#include <stdint.h>

typedef unsigned short u16;
typedef __bf16 bf16x8 __attribute__((ext_vector_type(8)));
typedef float f32x4 __attribute__((ext_vector_type(4)));
typedef u16 ushort8 __attribute__((ext_vector_type(8)));

#define SB 8
#define SS 2048
#define SH 1024
#define MTOT (SB*SS)
#define LOG2E 1.44269504088896f
#define SEXP (1.44269504088896f/32.f)   // exp(s/32) = exp2(s*SEXP)

typedef __attribute__((address_space(3))) void lds_void;
typedef __attribute__((address_space(1))) const void gbl_void;

__device__ __forceinline__ float bf2f(u16 v) {
    union { unsigned int u; float f; } x; x.u = ((unsigned int)v) << 16; return x.f;
}
__device__ __forceinline__ u16 f2bf(float f) {
    unsigned int u = __builtin_bit_cast(unsigned int, f);
    u += 0x7fffu + ((u >> 16) & 1u);
    return (u16)(u >> 16);
}

// ---------------- fp32 -> bf16 conversion, all four inputs in one kernel --
__global__ void cvt_all(const float* __restrict__ x,  const float* __restrict__ wq,
                        const float* __restrict__ wk, const float* __restrict__ wv,
                        u16* __restrict__ xb, u16* __restrict__ wb) {
    const int NX = MTOT * SH / 8, NW = SH * SH / 8;
    int i = blockIdx.x * 256 + threadIdx.x;
    const float* src; u16* dst; int off;
    if (i < NX)               { src = x;  dst = xb;                        off = i; }
    else if (i < NX + NW)     { src = wq; dst = wb;                        off = i - NX; }
    else if (i < NX + 2 * NW) { src = wk; dst = wb + (size_t)SH * SH;      off = i - NX - NW; }
    else                      { src = wv; dst = wb + (size_t)2 * SH * SH;  off = i - NX - 2 * NW; }
    const float4* p = (const float4*)(src + (size_t)off * 8);
    float4 a = p[0], b = p[1];
    ushort8 r;
    r[0] = f2bf(a.x); r[1] = f2bf(a.y); r[2] = f2bf(a.z); r[3] = f2bf(a.w);
    r[4] = f2bf(b.x); r[5] = f2bf(b.y); r[6] = f2bf(b.z); r[7] = f2bf(b.w);
    *(ushort8*)(dst + (size_t)off * 8) = r;
}

// ---------------- m97-style building blocks (scores/pv) -------------------
__device__ __forceinline__ void stage_tile(const u16* __restrict__ g, int ld,
                                           u16* lds, int w, int l) {
#pragma unroll
    for (int i = 0; i < 4; i++) {
        int chunk = i * 4 + w;
        int r = chunk * 8 + (l >> 3);
        int c = (l & 7) * 8;
        __builtin_amdgcn_global_load_lds(
            (gbl_void*)(g + (size_t)r * ld + c),
            (lds_void*)(lds + chunk * 512), 16, 0, 0);
    }
}

__device__ __forceinline__ void mfma_tile(const u16* As, const u16* Bs,
                                          f32x4 acc[4][4], int w, int l) {
    int wr = (w >> 1) * 64, wc = (w & 1) * 64;
    int lr = l & 15, lk = (l >> 4) * 8;
#pragma unroll
    for (int kk = 0; kk < 2; kk++) {
        bf16x8 af[4], bb[4];
#pragma unroll
        for (int m = 0; m < 4; m++)
            af[m] = *(const bf16x8*)(const void*)(As + (wr + m * 16 + lr) * 64 + kk * 32 + lk);
#pragma unroll
        for (int n = 0; n < 4; n++)
            bb[n] = *(const bf16x8*)(const void*)(Bs + (wc + n * 16 + lr) * 64 + kk * 32 + lk);
#pragma unroll
        for (int m = 0; m < 4; m++)
#pragma unroll
            for (int n = 0; n < 4; n++)
                acc[m][n] = __builtin_amdgcn_mfma_f32_16x16x32_bf16(af[m], bb[n], acc[m][n], 0, 0, 0);
    }
}

// ================= QKV: 256x256 tile, BK=64, 2 merged phases/K-tile =======
#define QNT 16   // K/64

#define STAGE8(gbase, ld, bufidx, h, t) do {                                          \
    const u16* _g = (gbase) + ((size_t)((h)*128 + srow)) * (ld) + (size_t)(t)*64 + scol; \
    u16* _d = &lds4[bufidx][((h)*128 + (w << 3)) * 64];                               \
    __builtin_amdgcn_global_load_lds((gbl_void*)_g, (lds_void*)_d, 16, 0, 0);         \
    __builtin_amdgcn_global_load_lds((gbl_void*)(_g + (size_t)64*(ld)),               \
                                     (lds_void*)(_d + 64*64), 16, 0, 0);              \
} while (0)

#define LDA8(mf, kkv) (*(const bf16x8*)(const void*)(Ab + (wr + (mf)*16 + rrow)*64 + rk##kkv))
#define LDB8(nf, kkv) (*(const bf16x8*)(const void*)(Bb + (wc + (nf)*16 + rrow)*64 + rk##kkv))

#define MFMA_PAIR(mf, A0, A1)                                                          \
    acc[mf][0] = __builtin_amdgcn_mfma_f32_16x16x32_bf16(A0, b00, acc[mf][0], 0,0,0);  \
    acc[mf][0] = __builtin_amdgcn_mfma_f32_16x16x32_bf16(A1, b01, acc[mf][0], 0,0,0);  \
    acc[mf][1] = __builtin_amdgcn_mfma_f32_16x16x32_bf16(A0, b10, acc[mf][1], 0,0,0);  \
    acc[mf][1] = __builtin_amdgcn_mfma_f32_16x16x32_bf16(A1, b11, acc[mf][1], 0,0,0);  \
    acc[mf][2] = __builtin_amdgcn_mfma_f32_16x16x32_bf16(A0, b20, acc[mf][2], 0,0,0);  \
    acc[mf][2] = __builtin_amdgcn_mfma_f32_16x16x32_bf16(A1, b21, acc[mf][2], 0,0,0);  \
    acc[mf][3] = __builtin_amdgcn_mfma_f32_16x16x32_bf16(A0, b30, acc[mf][3], 0,0,0);  \
    acc[mf][3] = __builtin_amdgcn_mfma_f32_16x16x32_bf16(A1, b31, acc[mf][3], 0,0,0);

#define PH_BAR_MID()                       \
    __builtin_amdgcn_sched_barrier(0);     \
    __builtin_amdgcn_s_barrier();          \
    __builtin_amdgcn_sched_barrier(0);

#define PH_BAR_END()                       \
    __builtin_amdgcn_sched_barrier(0);     \
    __builtin_amdgcn_s_barrier();          \
    __builtin_amdgcn_sched_barrier(0);

__global__ __launch_bounds__(512, 2) void gemm_qkv8(
    const u16* __restrict__ X, const u16* __restrict__ W,
    u16* __restrict__ Q, u16* __restrict__ Kd, u16* __restrict__ Vd) {
    __shared__ u16 lds4[4][256 * 64];

    int tid = threadIdx.x, w = tid >> 6, l = tid & 63;
    int bid = blockIdx.x;
    int wg = (bid & 7) * 96 + (bid >> 3);
    int mt = wg / 12, nb = wg % 12;

    const u16* gA = X + (size_t)mt * 256 * SH;
    const u16* gB = W + (size_t)nb * 256 * SH;

    int srow = (w << 3) + (l >> 3);
    int scol = (((l & 7) ^ ((l >> 3) & 7)) << 3);
    int wr = (w >> 2) * 128, wc = (w & 3) * 64;
    int rrow = l & 15;
    int rk0 = (((l >> 4) ^ (l & 7)) << 3);
    int rk1 = (((4 + (l >> 4)) ^ (l & 7)) << 3);

    f32x4 acc[8][4];
#pragma unroll
    for (int m = 0; m < 8; m++)
#pragma unroll
        for (int n = 0; n < 4; n++) acc[m][n] = (f32x4){0.f, 0.f, 0.f, 0.f};

    STAGE8(gA, SH, 0, 0, 0); STAGE8(gA, SH, 0, 1, 0);
    STAGE8(gB, SH, 2, 0, 0); STAGE8(gB, SH, 2, 1, 0);
    STAGE8(gB, SH, 3, 0, 1); STAGE8(gB, SH, 3, 1, 1);
    asm volatile("s_waitcnt vmcnt(4)" ::: "memory");
    __builtin_amdgcn_s_barrier();
    __builtin_amdgcn_sched_barrier(0);

    for (int t = 0; t < QNT; ++t) {
        const int p = t & 1;
        const u16* Ab = &lds4[p][0];
        const u16* Bb = &lds4[2 + p][0];

        // ---- phase A: all B-frags + A mf0-3; stage both A halves (t+1)
        bf16x8 b00 = LDB8(0, 0), b01 = LDB8(0, 1), b10 = LDB8(1, 0), b11 = LDB8(1, 1);
        bf16x8 b20 = LDB8(2, 0), b21 = LDB8(2, 1), b30 = LDB8(3, 0), b31 = LDB8(3, 1);
        {
            bf16x8 a00 = LDA8(0, 0), a01 = LDA8(0, 1), a10 = LDA8(1, 0), a11 = LDA8(1, 1);
            bf16x8 a20 = LDA8(2, 0), a21 = LDA8(2, 1), a30 = LDA8(3, 0), a31 = LDA8(3, 1);
            if (t + 1 < QNT) { STAGE8(gA, SH, (t + 1) & 1, 0, t + 1); STAGE8(gA, SH, (t + 1) & 1, 1, t + 1); }
            PH_BAR_MID();
            __builtin_amdgcn_s_setprio(1);
            MFMA_PAIR(0, a00, a01);
            MFMA_PAIR(1, a10, a11);
            MFMA_PAIR(2, a20, a21);
            MFMA_PAIR(3, a30, a31);
            __builtin_amdgcn_s_setprio(0);
            PH_BAR_END();
        }
        // ---- phase B: A mf4-7; stage both B halves (t+2); vmcnt gate
        {
            bf16x8 a00 = LDA8(4, 0), a01 = LDA8(4, 1), a10 = LDA8(5, 0), a11 = LDA8(5, 1);
            bf16x8 a20 = LDA8(6, 0), a21 = LDA8(6, 1), a30 = LDA8(7, 0), a31 = LDA8(7, 1);
            if (t + 2 < QNT) { STAGE8(gB, SH, 2 + (t & 1), 0, t + 2); STAGE8(gB, SH, 2 + (t & 1), 1, t + 2); }
            if (t + 2 < QNT)      asm volatile("s_waitcnt vmcnt(4)" ::: "memory");
            else if (t + 1 < QNT) asm volatile("s_waitcnt vmcnt(0)" ::: "memory");
            PH_BAR_MID();
            __builtin_amdgcn_s_setprio(1);
            MFMA_PAIR(4, a00, a01);
            MFMA_PAIR(5, a10, a11);
            MFMA_PAIR(6, a20, a21);
            MFMA_PAIR(7, a30, a31);
            __builtin_amdgcn_s_setprio(0);
            PH_BAR_END();
        }
    }

    // ---- epilogue: LDS-bounce, coalesced dwordx4 stores (2 half-passes)
    u16* outp = (nb < 4 ? Q : (nb < 8 ? Kd : Vd));
    size_t colb = (size_t)(nb & 3) * 256;
    int g = l >> 4, c = l & 15;
    u16* S = &lds4[0][0];                 // 128 rows x 264 u16 = 67584 B
    __syncthreads();                      // pipeline fully drained before reuse
#pragma unroll
    for (int pass = 0; pass < 2; ++pass) {
        if ((w >> 2) == pass) {
#pragma unroll
            for (int mf = 0; mf < 8; mf++)
#pragma unroll
                for (int j = 0; j < 4; j++) {
                    int rl = mf * 16 + g * 4 + j;
#pragma unroll
                    for (int nf = 0; nf < 4; nf++)
                        S[rl * 264 + wc + nf * 16 + c] = f2bf(acc[mf][nf][j]);
                }
        }
        __syncthreads();
#pragma unroll
        for (int q8 = 0; q8 < 8; ++q8) {
            int idx = q8 * 4096 + tid * 8;       // u16 units within 128x256 half-tile
            int row = idx >> 8;
            int colu = idx & 255;
            *(ushort8*)(outp + ((size_t)(mt * 256 + pass * 128 + row)) * SH + colb + colu)
                = *(const ushort8*)(S + row * 264 + colu);
        }
        __syncthreads();
    }
}

// ---------------- V transpose: Vt[b][o][s] = V[b*S+s][o] ------------------
__global__ void transpose_v(const u16* __restrict__ V, u16* __restrict__ Vt) {
    __shared__ u16 t[64][80];
    int s0 = blockIdx.x * 64, o0 = blockIdx.y * 64, b = blockIdx.z;
    const u16* src = V + (size_t)b * SS * SH;
    u16* dst = Vt + (size_t)b * SH * SS;
    int tid = threadIdx.x;
#pragma unroll
    for (int it = 0; it < 2; it++) {
        int idx = it * 256 + tid;
        int r = idx >> 3, gq = idx & 7;
        *(ushort8*)&t[r][gq * 8] = *(const ushort8*)&src[(size_t)(s0 + r) * SH + o0 + gq * 8];
    }
    __syncthreads();
#pragma unroll
    for (int it = 0; it < 2; it++) {
        int idx = it * 256 + tid;
        int rr = idx >> 3, cc = idx & 7;
        ushort8 v;
#pragma unroll
        for (int e = 0; e < 8; e++) v[e] = t[cc * 8 + e][rr];
        *(ushort8*)&dst[(size_t)(o0 + rr) * SS + s0 + cc * 8] = v;
    }
}

// ---------------- Scores: Ptilde = exp(qk/32) direct, + chunk sums --------
// XCD batch-affinity: grid 1088 = 8 XCD x 136 tiles; XCD x gets batch-major chunk
__global__ __launch_bounds__(256, 2) void gemm_scores(
    const u16* __restrict__ Q, const u16* __restrict__ K,
    u16* __restrict__ P, float* __restrict__ lb,
    const int* __restrict__ amask) {
    __shared__ u16 As[128 * 64];
    __shared__ u16 Bs[128 * 64];
    int tid = threadIdx.x, w = tid >> 6, l = tid & 63;
    int x = blockIdx.x;
    int wk_ = (x & 7) * 136 + (x >> 3);
    int b = wk_ / 136, t = wk_ % 136;
    int qt = (int)((sqrtf(8.f * (float)t + 1.f) - 1.f) * 0.5f);
    while ((qt + 1) * (qt + 2) / 2 <= t) qt++;
    while (qt * (qt + 1) / 2 > t) qt--;
    int kt = t - qt * (qt + 1) / 2;
    const u16* A = Q + ((size_t)b * SS + (size_t)qt * 128) * SH;
    const u16* Bt = K + ((size_t)b * SS + (size_t)kt * 128) * SH;
    f32x4 acc[4][4];
#pragma unroll
    for (int m = 0; m < 4; m++)
#pragma unroll
        for (int n = 0; n < 4; n++) acc[m][n] = (f32x4){0.f, 0.f, 0.f, 0.f};
    for (int k0 = 0; k0 < SH; k0 += 64) {
        stage_tile(A + k0, SH, As, w, l);
        stage_tile(Bt + k0, SH, Bs, w, l);
        __syncthreads();
        mfma_tile(As, Bs, acc, w, l);
        __syncthreads();
    }
    int wr = (w >> 1) * 64, wc = (w & 1) * 64, g = l >> 4, c = l & 15;
    int q0 = qt * 128 + wr;
    int k0w = kt * 128 + wc;
    int cglob = kt * 2 + (w & 1);
    u16* Pb = P + (size_t)b * SS * SS;
    float* lbb = lb + (size_t)b * SS * 32;
    int kg[4], kv[4];
#pragma unroll
    for (int n = 0; n < 4; n++) { kg[n] = k0w + n * 16 + c; kv[n] = amask[b * SS + kg[n]]; }
#pragma unroll
    for (int m = 0; m < 4; m++) {
#pragma unroll
        for (int j = 0; j < 4; j++) {
            int qg = q0 + m * 16 + g * 4 + j;
            float sv[4]; float ls = 0.f;
#pragma unroll
            for (int n = 0; n < 4; n++) {
                bool ok = (kg[n] <= qg) && (kv[n] != 0);
                float p = ok ? exp2f(acc[m][n][j] * SEXP) : 0.f;
                sv[n] = p; ls += p;
            }
#pragma unroll
            for (int d = 1; d < 16; d <<= 1) ls += __shfl_xor(ls, d, 64);
            size_t prow = (size_t)qg * SS;
#pragma unroll
            for (int n = 0; n < 4; n++) Pb[prow + kg[n]] = f2bf(sv[n]);
            if (c == 0) lbb[(size_t)qg * 32 + cglob] = ls;
        }
    }
}

// ---------------- Combine chunk sums -> per-row 1/L -----------------------
__global__ void combine_inv(const float* __restrict__ lb,
                            float* __restrict__ sb, const int* __restrict__ amask) {
    int row = blockIdx.x * 4 + (threadIdx.x >> 6);
    int l = threadIdx.x & 63;
    int b = row >> 11, q = row & 2047;
    int cmax = q >> 6;
    float L = (l < 32 && l <= cmax) ? lb[(size_t)row * 32 + l] : 0.f;
#pragma unroll
    for (int d = 1; d < 64; d <<= 1) L += __shfl_xor(L, d, 64);
    if (l == 0) {
        int qv = amask[b * SS + q];
        sb[row] = (qv != 0 && L > 0.f) ? 1.0f / L : 0.f;
    }
}

// ---------------- PV: O = (Ptilde @ Vt^T) * inv[row] ----------------------
// XCD batch-affinity: grid 1024 = 8 XCD x 128; longest q-tiles first per XCD
__global__ __launch_bounds__(256, 2) void gemm_pv(
    const u16* __restrict__ P, const u16* __restrict__ Vt,
    const float* __restrict__ sb, float* __restrict__ Out) {
    __shared__ u16 As[128 * 64];
    __shared__ u16 Bs[128 * 64];
    int tid = threadIdx.x, w = tid >> 6, l = tid & 63;
    int x = blockIdx.x;
    int wk_ = (x & 7) * 128 + (x >> 3);
    int b = wk_ >> 7;
    int r7 = wk_ & 127;
    int qt = 15 - (r7 >> 3), nt = r7 & 7;
    const u16* Ab = P + (size_t)b * SS * SS + (size_t)qt * 128 * SS;
    const u16* Bt = Vt + (size_t)b * SH * SS + (size_t)nt * 128 * SS;
    int ksize = (qt + 1) * 128;
    f32x4 acc[4][4];
#pragma unroll
    for (int m = 0; m < 4; m++)
#pragma unroll
        for (int n = 0; n < 4; n++) acc[m][n] = (f32x4){0.f, 0.f, 0.f, 0.f};
    for (int k0 = 0; k0 < ksize; k0 += 64) {
        stage_tile(Ab + k0, SS, As, w, l);
        stage_tile(Bt + k0, SS, Bs, w, l);
        __syncthreads();
        mfma_tile(As, Bs, acc, w, l);
        __syncthreads();
    }
    const float* sbq = sb + (size_t)b * SS + (size_t)qt * 128;
    float* out = Out + ((size_t)b * SS + (size_t)qt * 128) * SH + nt * 128;
    int wr = (w >> 1) * 64, wc = (w & 1) * 64, g = l >> 4, c = l & 15;
#pragma unroll
    for (int m = 0; m < 4; m++)
#pragma unroll
        for (int j = 0; j < 4; j++) {
            int row = wr + m * 16 + g * 4 + j;
            float scl = sbq[row];
            size_t ro = (size_t)row * SH;
#pragma unroll
            for (int n = 0; n < 4; n++)
                out[ro + wc + n * 16 + c] = acc[m][n][j] * scl;
        }
}

// ---------------- launch ---------------------------------------------------
extern "C" void kernel_launch(void* const* d_in, const int* in_sizes, int n_in,
                              void* d_out, int out_size, void* d_ws, size_t ws_size,
                              hipStream_t stream) {
    const float* x = (const float*)d_in[0];
    const int* amask = (const int*)d_in[1];
    const float* wq = (const float*)d_in[2];
    const float* wk = (const float*)d_in[3];
    const float* wv = (const float*)d_in[4];
    float* out = (float*)d_out;

    const size_t SZQ = (size_t)MTOT * SH * 2;
    const size_t SZSTAT = (size_t)MTOT * 32 * 4;
    char* ws = (char*)d_ws;
    u16* Q   = (u16*)(ws);
    u16* Kb  = (u16*)(ws + SZQ);
    u16* V   = (u16*)(ws + 2 * SZQ);
    u16* Vt  = (u16*)(ws + 3 * SZQ);
    float* lb = (float*)(ws + 4 * SZQ);
    float* sb = (float*)(ws + 4 * SZQ + SZSTAT);          // MTOT floats
    u16* P   = (u16*)(ws + 4 * SZQ + 3 * SZSTAT);
    u16* xb  = P;                                   // x_bf16 overlaps P (dead before scores)
    u16* wb  = P + (size_t)MTOT * SH;               // w_bf16 after x_bf16

    cvt_all<<<9728, 256, 0, stream>>>(x, wq, wk, wv, xb, wb);

    gemm_qkv8<<<768, 512, 0, stream>>>(xb, wb, Q, Kb, V);
    transpose_v<<<dim3(32, 16, 8), 256, 0, stream>>>(V, Vt);
    gemm_scores<<<1088, 256, 0, stream>>>(Q, Kb, P, lb, amask);
    combine_inv<<<4096, 256, 0, stream>>>(lb, sb, amask);
    gemm_pv<<<1024, 256, 0, stream>>>(P, Vt, sb, out);
}

// Round 9
// 341.076 us; speedup vs baseline: 1.2680x; 1.0212x over previous
//
#include <hip/hip_runtime.h>
#include <stdint.h>

typedef unsigned short u16;
typedef __bf16 bf16x8 __attribute__((ext_vector_type(8)));
typedef float f32x4 __attribute__((ext_vector_type(4)));
typedef u16 ushort8 __attribute__((ext_vector_type(8)));

#define SB 8
#define SS 2048
#define SH 1024
#define MTOT (SB*SS)
#define SEXP (1.44269504088896f/32.f)   // exp(s/32) = exp2(s*SEXP)

typedef __attribute__((address_space(3))) void lds_void;
typedef __attribute__((address_space(1))) const void gbl_void;

__device__ __forceinline__ float bf2f(u16 v) {
    union { unsigned int u; float f; } x; x.u = ((unsigned int)v) << 16; return x.f;
}
__device__ __forceinline__ u16 f2bf(float f) {
    unsigned int u = __builtin_bit_cast(unsigned int, f);
    u += 0x7fffu + ((u >> 16) & 1u);
    return (u16)(u >> 16);
}

// ---------------- fp32 -> bf16 conversion, all four inputs in one kernel --
__global__ void cvt_all(const float* __restrict__ x,  const float* __restrict__ wq,
                        const float* __restrict__ wk, const float* __restrict__ wv,
                        u16* __restrict__ xb, u16* __restrict__ wb) {
    const int NX = MTOT * SH / 8, NW = SH * SH / 8;
    int i = blockIdx.x * 256 + threadIdx.x;
    const float* src; u16* dst; int off;
    if (i < NX)               { src = x;  dst = xb;                        off = i; }
    else if (i < NX + NW)     { src = wq; dst = wb;                        off = i - NX; }
    else if (i < NX + 2 * NW) { src = wk; dst = wb + (size_t)SH * SH;      off = i - NX - NW; }
    else                      { src = wv; dst = wb + (size_t)2 * SH * SH;  off = i - NX - 2 * NW; }
    const float4* p = (const float4*)(src + (size_t)off * 8);
    float4 a = p[0], b = p[1];
    ushort8 r;
    r[0] = f2bf(a.x); r[1] = f2bf(a.y); r[2] = f2bf(a.z); r[3] = f2bf(a.w);
    r[4] = f2bf(b.x); r[5] = f2bf(b.y); r[6] = f2bf(b.z); r[7] = f2bf(b.w);
    *(ushort8*)(dst + (size_t)off * 8) = r;
}

// ---------------- m97-style building blocks (scores/pv) -------------------
__device__ __forceinline__ void stage_tile(const u16* __restrict__ g, int ld,
                                           u16* lds, int w, int l) {
#pragma unroll
    for (int i = 0; i < 4; i++) {
        int chunk = i * 4 + w;
        int r = chunk * 8 + (l >> 3);
        int c = (l & 7) * 8;
        __builtin_amdgcn_global_load_lds(
            (gbl_void*)(g + (size_t)r * ld + c),
            (lds_void*)(lds + chunk * 512), 16, 0, 0);
    }
}

__device__ __forceinline__ void mfma_tile(const u16* As, const u16* Bs,
                                          f32x4 acc[4][4], int w, int l) {
    int wr = (w >> 1) * 64, wc = (w & 1) * 64;
    int lr = l & 15, lk = (l >> 4) * 8;
#pragma unroll
    for (int kk = 0; kk < 2; kk++) {
        bf16x8 af[4], bb[4];
#pragma unroll
        for (int m = 0; m < 4; m++)
            af[m] = *(const bf16x8*)(const void*)(As + (wr + m * 16 + lr) * 64 + kk * 32 + lk);
#pragma unroll
        for (int n = 0; n < 4; n++)
            bb[n] = *(const bf16x8*)(const void*)(Bs + (wc + n * 16 + lr) * 64 + kk * 32 + lk);
#pragma unroll
        for (int m = 0; m < 4; m++)
#pragma unroll
            for (int n = 0; n < 4; n++)
                acc[m][n] = __builtin_amdgcn_mfma_f32_16x16x32_bf16(af[m], bb[n], acc[m][n], 0, 0, 0);
    }
}

// ================= QKV: 256x256 tile, BK=64, 4-phase pipeline (r6-verified)
// V output blocks (nb>=8) write DIRECTLY TRANSPOSED to Vt via the LDS bounce.
#define QNT 16   // K/64

#define STAGE8(gbase, ld, bufidx, h, t) do {                                          \
    const u16* _g = (gbase) + ((size_t)((h)*128 + srow)) * (ld) + (size_t)(t)*64 + scol; \
    u16* _d = &lds4[bufidx][((h)*128 + (w << 3)) * 64];                               \
    __builtin_amdgcn_global_load_lds((gbl_void*)_g, (lds_void*)_d, 16, 0, 0);         \
    __builtin_amdgcn_global_load_lds((gbl_void*)(_g + (size_t)64*(ld)),               \
                                     (lds_void*)(_d + 64*64), 16, 0, 0);              \
} while (0)

#define LDA8(mf, kkv) (*(const bf16x8*)(const void*)(Ab + (wr + (mf)*16 + rrow)*64 + rk##kkv))
#define LDB8(nf, kkv) (*(const bf16x8*)(const void*)(Bb + (wc + (nf)*16 + rrow)*64 + rk##kkv))

#define MFMA_PAIR(mf, A0, A1)                                                          \
    acc[mf][0] = __builtin_amdgcn_mfma_f32_16x16x32_bf16(A0, b00, acc[mf][0], 0,0,0);  \
    acc[mf][0] = __builtin_amdgcn_mfma_f32_16x16x32_bf16(A1, b01, acc[mf][0], 0,0,0);  \
    acc[mf][1] = __builtin_amdgcn_mfma_f32_16x16x32_bf16(A0, b10, acc[mf][1], 0,0,0);  \
    acc[mf][1] = __builtin_amdgcn_mfma_f32_16x16x32_bf16(A1, b11, acc[mf][1], 0,0,0);  \
    acc[mf][2] = __builtin_amdgcn_mfma_f32_16x16x32_bf16(A0, b20, acc[mf][2], 0,0,0);  \
    acc[mf][2] = __builtin_amdgcn_mfma_f32_16x16x32_bf16(A1, b21, acc[mf][2], 0,0,0);  \
    acc[mf][3] = __builtin_amdgcn_mfma_f32_16x16x32_bf16(A0, b30, acc[mf][3], 0,0,0);  \
    acc[mf][3] = __builtin_amdgcn_mfma_f32_16x16x32_bf16(A1, b31, acc[mf][3], 0,0,0);

#define PH_BAR_MID()                       \
    __builtin_amdgcn_sched_barrier(0);     \
    __builtin_amdgcn_s_barrier();          \
    __builtin_amdgcn_sched_barrier(0);

#define PH_BAR_END()                       \
    __builtin_amdgcn_sched_barrier(0);     \
    __builtin_amdgcn_s_barrier();          \
    __builtin_amdgcn_sched_barrier(0);

__global__ __launch_bounds__(512, 2) void gemm_qkv8(
    const u16* __restrict__ X, const u16* __restrict__ W,
    u16* __restrict__ Q, u16* __restrict__ Kd, u16* __restrict__ Vt) {
    __shared__ u16 lds4[4][256 * 64];

    int tid = threadIdx.x, w = tid >> 6, l = tid & 63;
    int bid = blockIdx.x;
    int wg = (bid & 7) * 96 + (bid >> 3);
    int mt = wg / 12, nb = wg % 12;

    const u16* gA = X + (size_t)mt * 256 * SH;
    const u16* gB = W + (size_t)nb * 256 * SH;

    int srow = (w << 3) + (l >> 3);
    int scol = (((l & 7) ^ ((l >> 3) & 7)) << 3);
    int wr = (w >> 2) * 128, wc = (w & 3) * 64;
    int rrow = l & 15;
    int rk0 = (((l >> 4) ^ (l & 7)) << 3);
    int rk1 = (((4 + (l >> 4)) ^ (l & 7)) << 3);

    f32x4 acc[8][4];
#pragma unroll
    for (int m = 0; m < 8; m++)
#pragma unroll
        for (int n = 0; n < 4; n++) acc[m][n] = (f32x4){0.f, 0.f, 0.f, 0.f};

    STAGE8(gA, SH, 0, 0, 0); STAGE8(gA, SH, 0, 1, 0);
    STAGE8(gB, SH, 2, 0, 0); STAGE8(gB, SH, 2, 1, 0);
    STAGE8(gB, SH, 3, 0, 1); STAGE8(gB, SH, 3, 1, 1);
    asm volatile("s_waitcnt vmcnt(4)" ::: "memory");
    __builtin_amdgcn_s_barrier();
    __builtin_amdgcn_sched_barrier(0);

    for (int t = 0; t < QNT; ++t) {
        const int p = t & 1;
        const u16* Ab = &lds4[p][0];
        const u16* Bb = &lds4[2 + p][0];

        bf16x8 b00 = LDB8(0, 0), b01 = LDB8(0, 1), b10 = LDB8(1, 0), b11 = LDB8(1, 1);
        bf16x8 b20 = LDB8(2, 0), b21 = LDB8(2, 1), b30 = LDB8(3, 0), b31 = LDB8(3, 1);
        {
            bf16x8 a00 = LDA8(0, 0), a01 = LDA8(0, 1), a10 = LDA8(1, 0), a11 = LDA8(1, 1);
            if (t + 1 < QNT) STAGE8(gA, SH, (t + 1) & 1, 0, t + 1);
            PH_BAR_MID();
            __builtin_amdgcn_s_setprio(1);
            MFMA_PAIR(0, a00, a01);
            MFMA_PAIR(1, a10, a11);
            __builtin_amdgcn_s_setprio(0);
            PH_BAR_END();
        }
        {
            bf16x8 a00 = LDA8(2, 0), a01 = LDA8(2, 1), a10 = LDA8(3, 0), a11 = LDA8(3, 1);
            if (t + 1 < QNT) STAGE8(gA, SH, (t + 1) & 1, 1, t + 1);
            PH_BAR_MID();
            __builtin_amdgcn_s_setprio(1);
            MFMA_PAIR(2, a00, a01);
            MFMA_PAIR(3, a10, a11);
            __builtin_amdgcn_s_setprio(0);
            PH_BAR_END();
        }
        {
            bf16x8 a00 = LDA8(4, 0), a01 = LDA8(4, 1), a10 = LDA8(5, 0), a11 = LDA8(5, 1);
            if (t + 2 < QNT) STAGE8(gB, SH, 2 + (t & 1), 0, t + 2);
            PH_BAR_MID();
            __builtin_amdgcn_s_setprio(1);
            MFMA_PAIR(4, a00, a01);
            MFMA_PAIR(5, a10, a11);
            __builtin_amdgcn_s_setprio(0);
            PH_BAR_END();
        }
        {
            bf16x8 a00 = LDA8(6, 0), a01 = LDA8(6, 1), a10 = LDA8(7, 0), a11 = LDA8(7, 1);
            if (t + 2 < QNT) STAGE8(gB, SH, 2 + (t & 1), 1, t + 2);
            if (t + 2 < QNT)      asm volatile("s_waitcnt vmcnt(4)" ::: "memory");
            else if (t + 1 < QNT) asm volatile("s_waitcnt vmcnt(0)" ::: "memory");
            PH_BAR_MID();
            __builtin_amdgcn_s_setprio(1);
            MFMA_PAIR(6, a00, a01);
            MFMA_PAIR(7, a10, a11);
            __builtin_amdgcn_s_setprio(0);
            PH_BAR_END();
        }
    }

    // ---- epilogue: LDS-bounce; Q/K coalesced rows, V transposed into Vt
    bool isV = (nb >= 8);
    u16* outp = (nb < 4 ? Q : Kd);
    size_t colb = (size_t)(nb & 3) * 256;
    int g = l >> 4, c = l & 15;
    u16* S = &lds4[0][0];                 // 128 rows x 264 u16
    int bb_ = mt >> 3;                    // batch
    u16* vtb = Vt + (size_t)bb_ * SH * SS;
    int sloc = (mt & 7) * 256;            // s offset within batch
    __syncthreads();
#pragma unroll
    for (int pass = 0; pass < 2; ++pass) {
        if ((w >> 2) == pass) {
#pragma unroll
            for (int mf = 0; mf < 8; mf++)
#pragma unroll
                for (int j = 0; j < 4; j++) {
                    int rl = mf * 16 + g * 4 + j;
#pragma unroll
                    for (int nf = 0; nf < 4; nf++)
                        S[rl * 264 + wc + nf * 16 + c] = f2bf(acc[mf][nf][j]);
                }
        }
        __syncthreads();
        if (!isV) {
#pragma unroll
            for (int q8 = 0; q8 < 8; ++q8) {
                int idx = q8 * 4096 + tid * 8;       // u16 units within 128x256 half-tile
                int row = idx >> 8;
                int colu = idx & 255;
                *(ushort8*)(outp + ((size_t)(mt * 256 + pass * 128 + row)) * SH + colb + colu)
                    = *(const ushort8*)(S + row * 264 + colu);
            }
        } else {
            // transposed copy-out: Vt[o][s] <- S[s][o]
            int sbase = sloc + pass * 128;
#pragma unroll
            for (int it = 0; it < 8; ++it) {
                int task = it * 512 + tid;           // 4096 tasks: 256 o x 16 s-groups
                int o = task & 255, sg = task >> 8;
                ushort8 v;
#pragma unroll
                for (int e = 0; e < 8; e++) v[e] = S[(sg * 8 + e) * 264 + o];
                *(ushort8*)(vtb + (size_t)(colb + o) * SS + sbase + sg * 8) = v;
            }
        }
        __syncthreads();
    }
}

// ---------------- Scores: Ptilde = exp(qk/32) direct, + chunk sums --------
__global__ __launch_bounds__(256, 2) void gemm_scores(
    const u16* __restrict__ Q, const u16* __restrict__ K,
    u16* __restrict__ P, float* __restrict__ lb,
    const int* __restrict__ amask) {
    __shared__ u16 As[128 * 64];
    __shared__ u16 Bs[128 * 64];
    int tid = threadIdx.x, w = tid >> 6, l = tid & 63;
    int x = blockIdx.x;
    int wk_ = (x & 7) * 136 + (x >> 3);
    int b = wk_ / 136, t = wk_ % 136;
    int qt = (int)((sqrtf(8.f * (float)t + 1.f) - 1.f) * 0.5f);
    while ((qt + 1) * (qt + 2) / 2 <= t) qt++;
    while (qt * (qt + 1) / 2 > t) qt--;
    int kt = t - qt * (qt + 1) / 2;
    const u16* A = Q + ((size_t)b * SS + (size_t)qt * 128) * SH;
    const u16* Bt = K + ((size_t)b * SS + (size_t)kt * 128) * SH;
    f32x4 acc[4][4];
#pragma unroll
    for (int m = 0; m < 4; m++)
#pragma unroll
        for (int n = 0; n < 4; n++) acc[m][n] = (f32x4){0.f, 0.f, 0.f, 0.f};
    for (int k0 = 0; k0 < SH; k0 += 64) {
        stage_tile(A + k0, SH, As, w, l);
        stage_tile(Bt + k0, SH, Bs, w, l);
        __syncthreads();
        mfma_tile(As, Bs, acc, w, l);
        __syncthreads();
    }
    int wr = (w >> 1) * 64, wc = (w & 1) * 64, g = l >> 4, c = l & 15;
    int q0 = qt * 128 + wr;
    int k0w = kt * 128 + wc;
    int cglob = kt * 2 + (w & 1);
    u16* Pb = P + (size_t)b * SS * SS;
    float* lbb = lb + (size_t)b * SS * 32;
    int kg[4], kv[4];
#pragma unroll
    for (int n = 0; n < 4; n++) { kg[n] = k0w + n * 16 + c; kv[n] = amask[b * SS + kg[n]]; }
#pragma unroll
    for (int m = 0; m < 4; m++) {
#pragma unroll
        for (int j = 0; j < 4; j++) {
            int qg = q0 + m * 16 + g * 4 + j;
            float sv[4]; float ls = 0.f;
#pragma unroll
            for (int n = 0; n < 4; n++) {
                bool ok = (kg[n] <= qg) && (kv[n] != 0);
                float p = ok ? exp2f(acc[m][n][j] * SEXP) : 0.f;
                sv[n] = p; ls += p;
            }
#pragma unroll
            for (int d = 1; d < 16; d <<= 1) ls += __shfl_xor(ls, d, 64);
            size_t prow = (size_t)qg * SS;
#pragma unroll
            for (int n = 0; n < 4; n++) Pb[prow + kg[n]] = f2bf(sv[n]);
            if (c == 0) lbb[(size_t)qg * 32 + cglob] = ls;
        }
    }
}

// ---------------- Combine chunk sums -> per-row 1/L (1 row/thread) --------
__global__ void combine_inv(const float* __restrict__ lb,
                            float* __restrict__ sb, const int* __restrict__ amask) {
    int row = blockIdx.x * 256 + threadIdx.x;
    int b = row >> 11, q = row & 2047;
    int cmax = q >> 6;
    const float* p = lb + (size_t)row * 32;
    float L = 0.f;
    for (int i = 0; i <= cmax; i++) L += p[i];
    sb[row] = (amask[b * SS + q] != 0 && L > 0.f) ? 1.0f / L : 0.f;
}

// ---------------- PV: O = (Ptilde @ Vt^T) * inv[row] ----------------------
__global__ __launch_bounds__(256, 2) void gemm_pv(
    const u16* __restrict__ P, const u16* __restrict__ Vt,
    const float* __restrict__ sb, float* __restrict__ Out) {
    __shared__ u16 As[128 * 64];
    __shared__ u16 Bs[128 * 64];
    int tid = threadIdx.x, w = tid >> 6, l = tid & 63;
    int x = blockIdx.x;
    int wk_ = (x & 7) * 128 + (x >> 3);
    int b = wk_ >> 7;
    int r7 = wk_ & 127;
    int qt = 15 - (r7 >> 3), nt = r7 & 7;
    const u16* Ab = P + (size_t)b * SS * SS + (size_t)qt * 128 * SS;
    const u16* Bt = Vt + (size_t)b * SH * SS + (size_t)nt * 128 * SS;
    int ksize = (qt + 1) * 128;
    f32x4 acc[4][4];
#pragma unroll
    for (int m = 0; m < 4; m++)
#pragma unroll
        for (int n = 0; n < 4; n++) acc[m][n] = (f32x4){0.f, 0.f, 0.f, 0.f};
    for (int k0 = 0; k0 < ksize; k0 += 64) {
        stage_tile(Ab + k0, SS, As, w, l);
        stage_tile(Bt + k0, SS, Bs, w, l);
        __syncthreads();
        mfma_tile(As, Bs, acc, w, l);
        __syncthreads();
    }
    const float* sbq = sb + (size_t)b * SS + (size_t)qt * 128;
    float* out = Out + ((size_t)b * SS + (size_t)qt * 128) * SH + nt * 128;
    int wr = (w >> 1) * 64, wc = (w & 1) * 64, g = l >> 4, c = l & 15;
#pragma unroll
    for (int m = 0; m < 4; m++)
#pragma unroll
        for (int j = 0; j < 4; j++) {
            int row = wr + m * 16 + g * 4 + j;
            float scl = sbq[row];
            size_t ro = (size_t)row * SH;
#pragma unroll
            for (int n = 0; n < 4; n++)
                out[ro + wc + n * 16 + c] = acc[m][n][j] * scl;
        }
}

// ---------------- launch ---------------------------------------------------
extern "C" void kernel_launch(void* const* d_in, const int* in_sizes, int n_in,
                              void* d_out, int out_size, void* d_ws, size_t ws_size,
                              hipStream_t stream) {
    const float* x = (const float*)d_in[0];
    const int* amask = (const int*)d_in[1];
    const float* wq = (const float*)d_in[2];
    const float* wk = (const float*)d_in[3];
    const float* wv = (const float*)d_in[4];
    float* out = (float*)d_out;

    const size_t SZQ = (size_t)MTOT * SH * 2;
    const size_t SZSTAT = (size_t)MTOT * 32 * 4;
    char* ws = (char*)d_ws;
    u16* Q   = (u16*)(ws);
    u16* Kb  = (u16*)(ws + SZQ);
    u16* Vt  = (u16*)(ws + 2 * SZQ);
    float* lb = (float*)(ws + 4 * SZQ);
    float* sb = (float*)(ws + 4 * SZQ + SZSTAT);          // MTOT floats
    u16* P   = (u16*)(ws + 4 * SZQ + 3 * SZSTAT);
    u16* xb  = P;                                   // x_bf16 overlaps P (dead before scores)
    u16* wb  = P + (size_t)MTOT * SH;               // w_bf16 after x_bf16

    cvt_all<<<9728, 256, 0, stream>>>(x, wq, wk, wv, xb, wb);

    gemm_qkv8<<<768, 512, 0, stream>>>(xb, wb, Q, Kb, Vt);
    gemm_scores<<<1088, 256, 0, stream>>>(Q, Kb, P, lb, amask);
    combine_inv<<<64, 256, 0, stream>>>(lb, sb, amask);
    gemm_pv<<<1024, 256, 0, stream>>>(P, Vt, sb, out);
}